// Round 1
// baseline (335.098 us; speedup 1.0000x reference)
//
#include <hip/hip_runtime.h>
#include <hip/hip_bf16.h>

// TextEncoderBlock: B=1 L=2048 EMBD=960 FFN=2560 QH=15 KVH=5 HD=64
// R0: full bf16-MFMA pipeline. 128x128-tile GEMMs (global_load_lds, 2-phase dbuf),
// flash attention (1 wave / 16 q rows), weights pre-transposed to bf16 NxK.

typedef __hip_bfloat16 bf16;
typedef __attribute__((ext_vector_type(8))) short bf16x8;
typedef __attribute__((ext_vector_type(4))) float f32x4;

#define EPS 1.1920929e-07f

__device__ __forceinline__ void gload_lds16(const bf16* g, bf16* l) {
  __builtin_amdgcn_global_load_lds(
      (const __attribute__((address_space(1))) unsigned int*)g,
      (__attribute__((address_space(3))) unsigned int*)l, 16, 0, 0);
}

__device__ __forceinline__ unsigned short f2bfu(float f) {
  __hip_bfloat16 b = __float2bfloat16(f);
  return *reinterpret_cast<unsigned short*>(&b);
}
__device__ __forceinline__ float bfu2f(unsigned short u) {
  return __uint_as_float(((unsigned int)u) << 16);
}

// ---------------- weight transpose: W (K x N fp32) -> WT (N x K bf16) -------
__launch_bounds__(256)
__global__ void transpose_bf16_k(const float* __restrict__ W, bf16* __restrict__ WT,
                                 int K, int N) {
  __shared__ float tile[64][65];
  const int k0 = blockIdx.y * 64, n0 = blockIdx.x * 64;
  const int tx = threadIdx.x & 63, ty = threadIdx.x >> 6;
#pragma unroll
  for (int i = 0; i < 16; ++i) {
    int r = ty + i * 4;
    tile[r][tx] = W[(size_t)(k0 + r) * N + n0 + tx];
  }
  __syncthreads();
#pragma unroll
  for (int i = 0; i < 16; ++i) {
    int r = ty + i * 4;
    WT[(size_t)(n0 + r) * K + k0 + tx] = __float2bfloat16(tile[tx][r]);
  }
}

// ---------------- rmsnorm: x (2048 x 960 fp32) -> out bf16 ------------------
__launch_bounds__(256)
__global__ void rmsnorm_k(const float* __restrict__ x, const float* __restrict__ g,
                          bf16* __restrict__ out) {
  const int row = blockIdx.x;
  const float* xr = x + (size_t)row * 960;
  const int t = threadIdx.x;
  float4 v = {0.f, 0.f, 0.f, 0.f};
  float ss = 0.f;
  if (t < 240) {
    v = *reinterpret_cast<const float4*>(&xr[t * 4]);
    ss = v.x * v.x + v.y * v.y + v.z * v.z + v.w * v.w;
  }
#pragma unroll
  for (int off = 32; off; off >>= 1) ss += __shfl_down(ss, off);
  __shared__ float red[4];
  __shared__ float s_scale;
  if ((t & 63) == 0) red[t >> 6] = ss;
  __syncthreads();
  if (t == 0) {
    float tot = red[0] + red[1] + red[2] + red[3];
    s_scale = rsqrtf(tot * (1.f / 960.f) + EPS);
  }
  __syncthreads();
  if (t < 240) {
    const float sc = s_scale;
    const float4 gv = *reinterpret_cast<const float4*>(&g[t * 4]);
    ushort4 o;
    o.x = f2bfu(v.x * sc * gv.x);
    o.y = f2bfu(v.y * sc * gv.y);
    o.z = f2bfu(v.z * sc * gv.z);
    o.w = f2bfu(v.w * sc * gv.w);
    *reinterpret_cast<ushort4*>(&out[(size_t)row * 960 + t * 4]) = o;
  }
}

// ---------------- GEMM: C(2048 x N) = A(2048 x K bf16) @ BT(N x K bf16)^T ---
// MODE 0: C fp32    MODE 1: C bf16    MODE 2: C fp32 += Res    MODE 3: split kv
template <int MODE>
__launch_bounds__(256)
__global__ void gemm_bt(const bf16* __restrict__ A, const bf16* __restrict__ BT,
                        const float* __restrict__ Res, float* __restrict__ Cf,
                        bf16* __restrict__ Cb, int N, int K) {
  __shared__ __align__(16) bf16 sA[2][128 * 32];
  __shared__ __align__(16) bf16 sB[2][128 * 32];
  const int t = threadIdx.x, w = t >> 6, lane = t & 63;
  const int lg = lane >> 4, lr = lane & 15;
  const int wm = w >> 1, wn = w & 1;
  const int m0 = blockIdx.y * 128, n0 = blockIdx.x * 128;
  f32x4 acc[4][4] = {};
  const int nsteps = K / 32;

  auto stage = [&](int buf, int ks) {
    const int k0 = ks * 32;
#pragma unroll
    for (int i = 0; i < 2; ++i) {
      int c = w * 128 + i * 64 + lane;
      int r = c >> 2, kc = (c & 3) * 8;
      gload_lds16(A + (size_t)(m0 + r) * K + k0 + kc, &sA[buf][c * 8]);
      int br = n0 + r;
      if (br >= N) br = N - 1;
      gload_lds16(BT + (size_t)br * K + k0 + kc, &sB[buf][c * 8]);
    }
  };

  stage(0, 0);
  __syncthreads();
  int cur = 0;
  for (int ks = 0; ks < nsteps; ++ks) {
    if (ks + 1 < nsteps) stage(cur ^ 1, ks + 1);
    bf16x8 af[4], bfr[4];
#pragma unroll
    for (int mi = 0; mi < 4; ++mi)
      af[mi] = *reinterpret_cast<const bf16x8*>(&sA[cur][(wm * 64 + mi * 16 + lr) * 32 + lg * 8]);
#pragma unroll
    for (int ni = 0; ni < 4; ++ni)
      bfr[ni] = *reinterpret_cast<const bf16x8*>(&sB[cur][(wn * 64 + ni * 16 + lr) * 32 + lg * 8]);
#pragma unroll
    for (int mi = 0; mi < 4; ++mi)
#pragma unroll
      for (int ni = 0; ni < 4; ++ni)
        acc[mi][ni] = __builtin_amdgcn_mfma_f32_16x16x32_bf16(af[mi], bfr[ni], acc[mi][ni], 0, 0, 0);
    __syncthreads();
    cur ^= 1;
  }

#pragma unroll
  for (int mi = 0; mi < 4; ++mi) {
    const int row = m0 + wm * 64 + mi * 16 + lg * 4;
#pragma unroll
    for (int ni = 0; ni < 4; ++ni) {
      const int col = n0 + wn * 64 + ni * 16 + lr;
      if (col < N) {
#pragma unroll
        for (int r = 0; r < 4; ++r) {
          float v = acc[mi][ni][r];
          size_t idx = (size_t)(row + r) * N + col;
          if (MODE == 0) {
            Cf[idx] = v;
          } else if (MODE == 1) {
            Cb[idx] = __float2bfloat16(v);
          } else if (MODE == 2) {
            Cf[idx] = v + Res[idx];
          } else {  // MODE 3: N=640, cols 0..319 -> k_out, 320..639 -> v_out
            int rr = row + r;
            if (col < 320)
              Cf[(size_t)rr * 320 + col] = v;
            else
              Cf[655360 + (size_t)rr * 320 + (col - 320)] = v;
          }
        }
      }
    }
  }
}

// ---------------- RoPE + V transpose ---------------------------------------
// qkv fp32 (2048 x 1600): q 0..959, k 960..1279, v 1280..1599
__launch_bounds__(256)
__global__ void rope_k(const float* __restrict__ qkv, bf16* __restrict__ qr,
                       bf16* __restrict__ kr, bf16* __restrict__ vT) {
  const int pos = blockIdx.x, t = threadIdx.x;
  __shared__ float ssin[32], scos[32];
  if (t < 32) {
    float inv = powf(10000.f, -(float)t * (1.f / 32.f));
    float rad = (float)pos * inv;
    ssin[t] = sinf(rad);
    scos[t] = cosf(rad);
  }
  __syncthreads();
  const float* row = qkv + (size_t)pos * 1600;
  for (int idx = t; idx < 480; idx += 256) {
    int h = idx >> 5, d = idx & 31;
    float x1 = row[h * 64 + d], x2 = row[h * 64 + d + 32];
    qr[(size_t)pos * 960 + h * 64 + d] = __float2bfloat16(x1 * scos[d] - x2 * ssin[d]);
    qr[(size_t)pos * 960 + h * 64 + d + 32] = __float2bfloat16(x2 * scos[d] + x1 * ssin[d]);
  }
  for (int idx = t; idx < 160; idx += 256) {
    int h = idx >> 5, d = idx & 31;
    float x1 = row[960 + h * 64 + d], x2 = row[960 + h * 64 + d + 32];
    kr[(size_t)pos * 320 + h * 64 + d] = __float2bfloat16(x1 * scos[d] - x2 * ssin[d]);
    kr[(size_t)pos * 320 + h * 64 + d + 32] = __float2bfloat16(x2 * scos[d] + x1 * ssin[d]);
  }
  for (int idx = t; idx < 320; idx += 256) {
    vT[(size_t)idx * 2048 + pos] = __float2bfloat16(row[1280 + idx]);
  }
}

// ---------------- flash attention ------------------------------------------
// grid (32 qblocks, 15 heads), 4 waves/block, 1 wave = 16 q rows.
__launch_bounds__(256)
__global__ void attn_k(const bf16* __restrict__ q, const bf16* __restrict__ k,
                       const bf16* __restrict__ vT, bf16* __restrict__ ctx) {
  const int head = blockIdx.y, qb = blockIdx.x;
  const int t = threadIdx.x, w = t >> 6, lane = t & 63;
  const int lg = lane >> 4, lr = lane & 15;
  const int qrow0 = qb * 64 + w * 16;
  const int kvh = head / 3;
  __shared__ __align__(16) bf16 p_lds[4][16][40];

  bf16x8 qf[2];
#pragma unroll
  for (int dk = 0; dk < 2; ++dk)
    qf[dk] = *reinterpret_cast<const bf16x8*>(
        &q[(size_t)(qrow0 + lr) * 960 + head * 64 + dk * 32 + lg * 8]);

  f32x4 acc[4] = {};
  float mrun[4], lrun[4];
#pragma unroll
  for (int r = 0; r < 4; ++r) { mrun[r] = -1e30f; lrun[r] = 0.f; }

  const int ktiles = (qrow0 + 15) / 32 + 1;
  for (int kb = 0; kb < ktiles; ++kb) {
    f32x4 s[2] = {};
#pragma unroll
    for (int nt = 0; nt < 2; ++nt)
#pragma unroll
      for (int dk = 0; dk < 2; ++dk) {
        bf16x8 kf = *reinterpret_cast<const bf16x8*>(
            &k[(size_t)(kb * 32 + nt * 16 + lr) * 320 + kvh * 64 + dk * 32 + lg * 8]);
        s[nt] = __builtin_amdgcn_mfma_f32_16x16x32_bf16(qf[dk], kf, s[nt], 0, 0, 0);
      }
    // scale + causal mask
#pragma unroll
    for (int nt = 0; nt < 2; ++nt) {
      const int col = kb * 32 + nt * 16 + lr;
#pragma unroll
      for (int r = 0; r < 4; ++r) {
        const int rowi = qrow0 + lg * 4 + r;
        float sv = s[nt][r] * 0.125f;
        s[nt][r] = (col > rowi) ? -1e30f : sv;
      }
    }
    float tm[4], ef[4], ts[4];
#pragma unroll
    for (int r = 0; r < 4; ++r) tm[r] = fmaxf(s[0][r], s[1][r]);
#pragma unroll
    for (int msk = 1; msk <= 8; msk <<= 1)
#pragma unroll
      for (int r = 0; r < 4; ++r) tm[r] = fmaxf(tm[r], __shfl_xor(tm[r], msk));
#pragma unroll
    for (int r = 0; r < 4; ++r) {
      float mn = fmaxf(mrun[r], tm[r]);
      ef[r] = __expf(mrun[r] - mn);
      mrun[r] = mn;
      ts[r] = 0.f;
    }
#pragma unroll
    for (int nt = 0; nt < 2; ++nt)
#pragma unroll
      for (int r = 0; r < 4; ++r) {
        float p = __expf(s[nt][r] - mrun[r]);
        s[nt][r] = p;
        ts[r] += p;
      }
#pragma unroll
    for (int msk = 1; msk <= 8; msk <<= 1)
#pragma unroll
      for (int r = 0; r < 4; ++r) ts[r] += __shfl_xor(ts[r], msk);
#pragma unroll
    for (int r = 0; r < 4; ++r) lrun[r] = lrun[r] * ef[r] + ts[r];
#pragma unroll
    for (int nt2 = 0; nt2 < 4; ++nt2)
#pragma unroll
      for (int r = 0; r < 4; ++r) acc[nt2][r] *= ef[r];
    // P (C-layout) -> LDS -> A-fragment layout
#pragma unroll
    for (int nt = 0; nt < 2; ++nt)
#pragma unroll
      for (int r = 0; r < 4; ++r)
        p_lds[w][lg * 4 + r][nt * 16 + lr] = __float2bfloat16(s[nt][r]);
    bf16x8 pf = *reinterpret_cast<const bf16x8*>(&p_lds[w][lr][lg * 8]);
#pragma unroll
    for (int nt2 = 0; nt2 < 4; ++nt2) {
      bf16x8 vf = *reinterpret_cast<const bf16x8*>(
          &vT[(size_t)(kvh * 64 + nt2 * 16 + lr) * 2048 + kb * 32 + lg * 8]);
      acc[nt2] = __builtin_amdgcn_mfma_f32_16x16x32_bf16(pf, vf, acc[nt2], 0, 0, 0);
    }
  }
#pragma unroll
  for (int nt2 = 0; nt2 < 4; ++nt2)
#pragma unroll
    for (int r = 0; r < 4; ++r) {
      float o = acc[nt2][r] / lrun[r];
      ctx[(size_t)(qrow0 + lg * 4 + r) * 960 + head * 64 + nt2 * 16 + lr] = __float2bfloat16(o);
    }
}

// ---------------- SwiGLU activation ----------------------------------------
__launch_bounds__(256)
__global__ void act_k(const bf16* __restrict__ gu, bf16* __restrict__ act) {
  const int i = blockIdx.x * 256 + threadIdx.x;  // one 8-vec per thread
  if (i >= 2048 * 320) return;
  const int row = i / 320, col = (i % 320) * 8;
  union { bf16x8 v; unsigned short u[8]; } g_, u_, o_;
  g_.v = *reinterpret_cast<const bf16x8*>(&gu[(size_t)row * 5120 + col]);
  u_.v = *reinterpret_cast<const bf16x8*>(&gu[(size_t)row * 5120 + 2560 + col]);
#pragma unroll
  for (int j = 0; j < 8; ++j) {
    float gf = bfu2f(g_.u[j]), uf = bfu2f(u_.u[j]);
    float s = gf / (1.f + __expf(-gf));
    o_.u[j] = f2bfu(s * uf);
  }
  *reinterpret_cast<bf16x8*>(&act[(size_t)row * 2560 + col]) = o_.v;
}

// ---------------- launch ----------------------------------------------------
extern "C" void kernel_launch(void* const* d_in, const int* in_sizes, int n_in,
                              void* d_out, int out_size, void* d_ws, size_t ws_size,
                              hipStream_t stream) {
  const float* x  = (const float*)d_in[0];
  const float* wq = (const float*)d_in[1];
  const float* wk = (const float*)d_in[2];
  const float* wv = (const float*)d_in[3];
  const float* wo = (const float*)d_in[4];
  const float* wg = (const float*)d_in[5];
  const float* wu = (const float*)d_in[6];
  const float* wd = (const float*)d_in[7];
  const float* g1 = (const float*)d_in[8];
  const float* g2 = (const float*)d_in[9];
  float* out = (float*)d_out;

  char* ws = (char*)d_ws;
  bf16*  wT   = (bf16*)ws;                       // 9,830,400 bf16
  float* qkv  = (float*)(ws + 19660800);         // 2048x1600 fp32
  bf16*  hbuf = (bf16*)(ws + 32768000);          // 2048x960 (h, h2, hr)
  bf16*  qr   = (bf16*)(ws + 36700160);          // 2048x960
  bf16*  kr   = (bf16*)(ws + 40632320);          // 2048x320
  bf16*  vT   = (bf16*)(ws + 41943040);          // 320x2048
  bf16*  ctx  = (bf16*)(ws + 43253760);          // 2048x960
  float* x2   = (float*)(ws + 47185920);         // 2048x960 fp32
  bf16*  gu   = (bf16*)(ws + 55050240);          // 2048x5120
  bf16*  actb = (bf16*)(ws + 19660800);          // reuse qkv region (2048x2560)

  // transposed-weight element offsets within wT
  bf16* wqT = wT;             // 960x960
  bf16* wkT = wT + 921600;    // 320x960
  // wvT = wT + 1228800
  bf16* woT = wT + 1536000;   // 960x960
  bf16* wgT = wT + 2457600;   // 2560x960 (wuT contiguous after => combined 5120x960)
  bf16* wuT = wT + 4915200;
  bf16* wdT = wT + 7372800;   // 960x2560

  dim3 blk(256);
  transpose_bf16_k<<<dim3(15, 15), blk, 0, stream>>>(wq, wqT, 960, 960);
  transpose_bf16_k<<<dim3(5, 15), blk, 0, stream>>>(wk, wkT, 960, 320);
  transpose_bf16_k<<<dim3(5, 15), blk, 0, stream>>>(wv, wT + 1228800, 960, 320);
  transpose_bf16_k<<<dim3(15, 15), blk, 0, stream>>>(wo, woT, 960, 960);
  transpose_bf16_k<<<dim3(40, 15), blk, 0, stream>>>(wg, wgT, 960, 2560);
  transpose_bf16_k<<<dim3(40, 15), blk, 0, stream>>>(wu, wuT, 960, 2560);
  transpose_bf16_k<<<dim3(15, 40), blk, 0, stream>>>(wd, wdT, 2560, 960);

  rmsnorm_k<<<2048, blk, 0, stream>>>(x, g1, hbuf);
  gemm_bt<0><<<dim3(13, 16), blk, 0, stream>>>(hbuf, wT, nullptr, qkv, nullptr, 1600, 960);
  rope_k<<<2048, blk, 0, stream>>>(qkv, qr, kr, vT);
  attn_k<<<dim3(32, 15), blk, 0, stream>>>(qr, kr, vT, ctx);
  gemm_bt<2><<<dim3(8, 16), blk, 0, stream>>>(ctx, woT, x, x2, nullptr, 960, 960);
  rmsnorm_k<<<2048, blk, 0, stream>>>(x2, g2, hbuf);
  gemm_bt<1><<<dim3(40, 16), blk, 0, stream>>>(hbuf, wgT, nullptr, nullptr, gu, 5120, 960);
  act_k<<<2560, blk, 0, stream>>>(gu, actb);
  gemm_bt<2><<<dim3(8, 16), blk, 0, stream>>>(actb, wdT, x2, out, nullptr, 960, 2560);
  rmsnorm_k<<<2048, blk, 0, stream>>>(x2, g1, hbuf);
  gemm_bt<3><<<dim3(5, 16), blk, 0, stream>>>(hbuf, wkT, nullptr, out + 1966080, nullptr, 640, 960);
}

// Round 2
// 316.782 us; speedup vs baseline: 1.0578x; 1.0578x over previous
//
#include <hip/hip_runtime.h>
#include <hip/hip_bf16.h>

// TextEncoderBlock R1: split-KV flash attention (+merge), RoPE fused into QKV
// GEMM epilogue, 64x128-tile GEMMs for small-N projections.
// B=1 L=2048 EMBD=960 FFN=2560 QH=15 KVH=5 HD=64

typedef __hip_bfloat16 bf16;
typedef __attribute__((ext_vector_type(8))) short bf16x8;
typedef __attribute__((ext_vector_type(4))) float f32x4;

#define EPS 1.1920929e-07f

__device__ __forceinline__ void gload_lds16(const bf16* g, bf16* l) {
  __builtin_amdgcn_global_load_lds(
      (const __attribute__((address_space(1))) unsigned int*)g,
      (__attribute__((address_space(3))) unsigned int*)l, 16, 0, 0);
}

__device__ __forceinline__ unsigned short f2bfu(float f) {
  __hip_bfloat16 b = __float2bfloat16(f);
  return *reinterpret_cast<unsigned short*>(&b);
}
__device__ __forceinline__ float bfu2f(unsigned short u) {
  return __uint_as_float(((unsigned int)u) << 16);
}

// ---------------- weight transpose: W (K x N fp32) -> WT (N x K bf16) -------
__launch_bounds__(256)
__global__ void transpose_bf16_k(const float* __restrict__ W, bf16* __restrict__ WT,
                                 int K, int N) {
  __shared__ float tile[64][65];
  const int k0 = blockIdx.y * 64, n0 = blockIdx.x * 64;
  const int tx = threadIdx.x & 63, ty = threadIdx.x >> 6;
#pragma unroll
  for (int i = 0; i < 16; ++i) {
    int r = ty + i * 4;
    tile[r][tx] = W[(size_t)(k0 + r) * N + n0 + tx];
  }
  __syncthreads();
#pragma unroll
  for (int i = 0; i < 16; ++i) {
    int r = ty + i * 4;
    WT[(size_t)(n0 + r) * K + k0 + tx] = __float2bfloat16(tile[tx][r]);
  }
}

// ---------------- cos/sin table: cstab[pos][d] = (cos, sin), d=0..31 --------
__launch_bounds__(256)
__global__ void rope_tab_k(float2* __restrict__ cstab) {
  const int idx = blockIdx.x * 256 + threadIdx.x;
  if (idx >= 2048 * 32) return;
  const int pos = idx >> 5, d = idx & 31;
  float inv = powf(10000.f, -(float)d * (1.f / 32.f));
  float rad = (float)pos * inv;
  cstab[idx] = make_float2(cosf(rad), sinf(rad));
}

// ---------------- rmsnorm: x (2048 x 960 fp32) -> out bf16 ------------------
__launch_bounds__(256)
__global__ void rmsnorm_k(const float* __restrict__ x, const float* __restrict__ g,
                          bf16* __restrict__ out) {
  const int row = blockIdx.x;
  const float* xr = x + (size_t)row * 960;
  const int t = threadIdx.x;
  float4 v = {0.f, 0.f, 0.f, 0.f};
  float ss = 0.f;
  if (t < 240) {
    v = *reinterpret_cast<const float4*>(&xr[t * 4]);
    ss = v.x * v.x + v.y * v.y + v.z * v.z + v.w * v.w;
  }
#pragma unroll
  for (int off = 32; off; off >>= 1) ss += __shfl_down(ss, off);
  __shared__ float red[4];
  __shared__ float s_scale;
  if ((t & 63) == 0) red[t >> 6] = ss;
  __syncthreads();
  if (t == 0) {
    float tot = red[0] + red[1] + red[2] + red[3];
    s_scale = rsqrtf(tot * (1.f / 960.f) + EPS);
  }
  __syncthreads();
  if (t < 240) {
    const float sc = s_scale;
    const float4 gv = *reinterpret_cast<const float4*>(&g[t * 4]);
    ushort4 o;
    o.x = f2bfu(v.x * sc * gv.x);
    o.y = f2bfu(v.y * sc * gv.y);
    o.z = f2bfu(v.z * sc * gv.z);
    o.w = f2bfu(v.w * sc * gv.w);
    *reinterpret_cast<ushort4*>(&out[(size_t)row * 960 + t * 4]) = o;
  }
}

// ---------------- GEMM 128x128: C(2048 x N) = A @ BT^T ----------------------
// MODE 1: C bf16 (used for gate/up)
template <int MODE>
__launch_bounds__(256)
__global__ void gemm_bt(const bf16* __restrict__ A, const bf16* __restrict__ BT,
                        const float* __restrict__ Res, float* __restrict__ Cf,
                        bf16* __restrict__ Cb, int N, int K) {
  __shared__ __align__(16) bf16 sA[2][128 * 32];
  __shared__ __align__(16) bf16 sB[2][128 * 32];
  const int t = threadIdx.x, w = t >> 6, lane = t & 63;
  const int lg = lane >> 4, lr = lane & 15;
  const int wm = w >> 1, wn = w & 1;
  const int m0 = blockIdx.y * 128, n0 = blockIdx.x * 128;
  f32x4 acc[4][4] = {};
  const int nsteps = K / 32;

  auto stage = [&](int buf, int ks) {
    const int k0 = ks * 32;
#pragma unroll
    for (int i = 0; i < 2; ++i) {
      int c = w * 128 + i * 64 + lane;
      int r = c >> 2, kc = (c & 3) * 8;
      gload_lds16(A + (size_t)(m0 + r) * K + k0 + kc, &sA[buf][c * 8]);
      int br = n0 + r;
      if (br >= N) br = N - 1;
      gload_lds16(BT + (size_t)br * K + k0 + kc, &sB[buf][c * 8]);
    }
  };

  stage(0, 0);
  __syncthreads();
  int cur = 0;
  for (int ks = 0; ks < nsteps; ++ks) {
    if (ks + 1 < nsteps) stage(cur ^ 1, ks + 1);
    bf16x8 af[4], bfr[4];
#pragma unroll
    for (int mi = 0; mi < 4; ++mi)
      af[mi] = *reinterpret_cast<const bf16x8*>(&sA[cur][(wm * 64 + mi * 16 + lr) * 32 + lg * 8]);
#pragma unroll
    for (int ni = 0; ni < 4; ++ni)
      bfr[ni] = *reinterpret_cast<const bf16x8*>(&sB[cur][(wn * 64 + ni * 16 + lr) * 32 + lg * 8]);
#pragma unroll
    for (int mi = 0; mi < 4; ++mi)
#pragma unroll
      for (int ni = 0; ni < 4; ++ni)
        acc[mi][ni] = __builtin_amdgcn_mfma_f32_16x16x32_bf16(af[mi], bfr[ni], acc[mi][ni], 0, 0, 0);
    __syncthreads();
    cur ^= 1;
  }

#pragma unroll
  for (int mi = 0; mi < 4; ++mi) {
    const int row = m0 + wm * 64 + mi * 16 + lg * 4;
#pragma unroll
    for (int ni = 0; ni < 4; ++ni) {
      const int col = n0 + wn * 64 + ni * 16 + lr;
      if (col < N) {
#pragma unroll
        for (int r = 0; r < 4; ++r) {
          float v = acc[mi][ni][r];
          size_t idx = (size_t)(row + r) * N + col;
          if (MODE == 1) Cb[idx] = __float2bfloat16(v);
        }
      }
    }
  }
}

// ---------------- GEMM 64x128 (small N): MODE 2 += Res, MODE 3 split kv -----
template <int MODE>
__launch_bounds__(256)
__global__ void gemm_bt64(const bf16* __restrict__ A, const bf16* __restrict__ BT,
                          const float* __restrict__ Res, float* __restrict__ Cf,
                          int N, int K) {
  __shared__ __align__(16) bf16 sA[2][64 * 32];
  __shared__ __align__(16) bf16 sB[2][128 * 32];
  const int t = threadIdx.x, w = t >> 6, lane = t & 63;
  const int lg = lane >> 4, lr = lane & 15;
  const int wm = w >> 1, wn = w & 1;
  const int m0 = blockIdx.y * 64, n0 = blockIdx.x * 128;
  f32x4 acc[2][4] = {};
  const int nsteps = K / 32;

  auto stage = [&](int buf, int ks) {
    const int k0 = ks * 32;
    {
      int c = t;  // 256 chunks cover 64x32
      int r = c >> 2, kc = (c & 3) * 8;
      gload_lds16(A + (size_t)(m0 + r) * K + k0 + kc, &sA[buf][c * 8]);
    }
#pragma unroll
    for (int i = 0; i < 2; ++i) {
      int c = i * 256 + t;
      int r = c >> 2, kc = (c & 3) * 8;
      int br = n0 + r;
      if (br >= N) br = N - 1;
      gload_lds16(BT + (size_t)br * K + k0 + kc, &sB[buf][c * 8]);
    }
  };

  stage(0, 0);
  __syncthreads();
  int cur = 0;
  for (int ks = 0; ks < nsteps; ++ks) {
    if (ks + 1 < nsteps) stage(cur ^ 1, ks + 1);
    bf16x8 af[2], bfr[4];
#pragma unroll
    for (int mi = 0; mi < 2; ++mi)
      af[mi] = *reinterpret_cast<const bf16x8*>(&sA[cur][(wm * 32 + mi * 16 + lr) * 32 + lg * 8]);
#pragma unroll
    for (int ni = 0; ni < 4; ++ni)
      bfr[ni] = *reinterpret_cast<const bf16x8*>(&sB[cur][(wn * 64 + ni * 16 + lr) * 32 + lg * 8]);
#pragma unroll
    for (int mi = 0; mi < 2; ++mi)
#pragma unroll
      for (int ni = 0; ni < 4; ++ni)
        acc[mi][ni] = __builtin_amdgcn_mfma_f32_16x16x32_bf16(af[mi], bfr[ni], acc[mi][ni], 0, 0, 0);
    __syncthreads();
    cur ^= 1;
  }

#pragma unroll
  for (int mi = 0; mi < 2; ++mi) {
    const int row = m0 + wm * 32 + mi * 16 + lg * 4;
#pragma unroll
    for (int ni = 0; ni < 4; ++ni) {
      const int col = n0 + wn * 64 + ni * 16 + lr;
      if (col < N) {
#pragma unroll
        for (int r = 0; r < 4; ++r) {
          float v = acc[mi][ni][r];
          size_t idx = (size_t)(row + r) * N + col;
          if (MODE == 2) {
            Cf[idx] = v + Res[idx];
          } else {  // MODE 3: N=640 -> k_out | v_out
            int rr = row + r;
            if (col < 320)
              Cf[(size_t)rr * 320 + col] = v;
            else
              Cf[655360 + (size_t)rr * 320 + (col - 320)] = v;
          }
        }
      }
    }
  }
}

// ---------------- QKV GEMM 128x128 with fused RoPE + V-transpose epilogue ---
// N=1600 (q 0..959 | k 960..1279 | v 1280..1599), K=960
__launch_bounds__(256)
__global__ void gemm_qkv(const bf16* __restrict__ A, const bf16* __restrict__ BT,
                         const float2* __restrict__ cstab, bf16* __restrict__ qr,
                         bf16* __restrict__ kr, bf16* __restrict__ vT) {
  const int N = 1600, K = 960;
  __shared__ __align__(16) bf16 sA[2][128 * 32];
  __shared__ __align__(16) bf16 sB[2][128 * 32];
  const int t = threadIdx.x, w = t >> 6, lane = t & 63;
  const int lg = lane >> 4, lr = lane & 15;
  const int wm = w >> 1, wn = w & 1;
  const int m0 = blockIdx.y * 128, n0 = blockIdx.x * 128;
  f32x4 acc[4][4] = {};
  const int nsteps = K / 32;

  auto stage = [&](int buf, int ks) {
    const int k0 = ks * 32;
#pragma unroll
    for (int i = 0; i < 2; ++i) {
      int c = w * 128 + i * 64 + lane;
      int r = c >> 2, kc = (c & 3) * 8;
      gload_lds16(A + (size_t)(m0 + r) * K + k0 + kc, &sA[buf][c * 8]);
      int br = n0 + r;
      if (br >= N) br = N - 1;
      gload_lds16(BT + (size_t)br * K + k0 + kc, &sB[buf][c * 8]);
    }
  };

  stage(0, 0);
  __syncthreads();
  int cur = 0;
  for (int ks = 0; ks < nsteps; ++ks) {
    if (ks + 1 < nsteps) stage(cur ^ 1, ks + 1);
    bf16x8 af[4], bfr[4];
#pragma unroll
    for (int mi = 0; mi < 4; ++mi)
      af[mi] = *reinterpret_cast<const bf16x8*>(&sA[cur][(wm * 64 + mi * 16 + lr) * 32 + lg * 8]);
#pragma unroll
    for (int ni = 0; ni < 4; ++ni)
      bfr[ni] = *reinterpret_cast<const bf16x8*>(&sB[cur][(wn * 64 + ni * 16 + lr) * 32 + lg * 8]);
#pragma unroll
    for (int mi = 0; mi < 4; ++mi)
#pragma unroll
      for (int ni = 0; ni < 4; ++ni)
        acc[mi][ni] = __builtin_amdgcn_mfma_f32_16x16x32_bf16(af[mi], bfr[ni], acc[mi][ni], 0, 0, 0);
    __syncthreads();
    cur ^= 1;
  }

  const int colbase = n0 + wn * 64;  // 64-aligned -> exactly one segment type
  if (colbase >= 1600) return;
  if (colbase < 1280) {
    // q or k window: apply RoPE. Pairs: acc[mi][ni] (d=ni*16+lr) with acc[mi][ni+2].
    const bool isq = colbase < 960;
    bf16* dst = isq ? qr : kr;
    const int ncols = isq ? 960 : 320;
    const int cb = isq ? colbase : colbase - 960;
#pragma unroll
    for (int mi = 0; mi < 4; ++mi) {
      const int row = m0 + wm * 64 + mi * 16 + lg * 4;
#pragma unroll
      for (int ni = 0; ni < 2; ++ni) {
        const int d = ni * 16 + lr;  // 0..31 within head
#pragma unroll
        for (int r = 0; r < 4; ++r) {
          const int pos = row + r;
          float2 cs = cstab[pos * 32 + d];
          float x1 = acc[mi][ni][r], x2 = acc[mi][ni + 2][r];
          dst[(size_t)pos * ncols + cb + d] = __float2bfloat16(x1 * cs.x - x2 * cs.y);
          dst[(size_t)pos * ncols + cb + d + 32] = __float2bfloat16(x2 * cs.x + x1 * cs.y);
        }
      }
    }
  } else {
    // v window: write transposed vT[vc][pos], 4 rows packed per store
#pragma unroll
    for (int mi = 0; mi < 4; ++mi) {
      const int row = m0 + wm * 64 + mi * 16 + lg * 4;
#pragma unroll
      for (int ni = 0; ni < 4; ++ni) {
        const int vc = colbase - 1280 + ni * 16 + lr;
        ushort4 pk;
        pk.x = f2bfu(acc[mi][ni][0]);
        pk.y = f2bfu(acc[mi][ni][1]);
        pk.z = f2bfu(acc[mi][ni][2]);
        pk.w = f2bfu(acc[mi][ni][3]);
        *reinterpret_cast<ushort4*>(&vT[(size_t)vc * 2048 + row]) = pk;
      }
    }
  }
}

// ---------------- split-KV flash attention ----------------------------------
// grid (32 qb, 15 head, 4 chunk); wave w handles q-tile qt=qb*4+w (16 rows),
// chunk c covers kv-tiles [c*16, c*16+16) clipped to causal range.
__launch_bounds__(256)
__global__ void attn_part_k(const bf16* __restrict__ q, const bf16* __restrict__ k,
                            const bf16* __restrict__ vT, float* __restrict__ pacc,
                            float* __restrict__ pml) {
  const int head = blockIdx.y, qb = blockIdx.x, c = blockIdx.z;
  const int t = threadIdx.x, w = t >> 6, lane = t & 63;
  const int lg = lane >> 4, lr = lane & 15;
  const int qt = qb * 4 + w;
  const int qrow0 = qt * 16;
  const int kvh = head / 3;
  const int ntiles = (qrow0 + 16 + 31) / 32;
  const int t0 = c * 16;
  if (t0 >= ntiles) return;
  const int t1 = min(t0 + 16, ntiles);
  __shared__ __align__(16) bf16 p_lds[4][16][40];

  bf16x8 qf[2];
#pragma unroll
  for (int dk = 0; dk < 2; ++dk)
    qf[dk] = *reinterpret_cast<const bf16x8*>(
        &q[(size_t)(qrow0 + lr) * 960 + head * 64 + dk * 32 + lg * 8]);

  f32x4 acc[4] = {};
  float mrun[4], lrun[4];
#pragma unroll
  for (int r = 0; r < 4; ++r) { mrun[r] = -1e30f; lrun[r] = 0.f; }

  for (int kb = t0; kb < t1; ++kb) {
    f32x4 s[2] = {};
#pragma unroll
    for (int nt = 0; nt < 2; ++nt)
#pragma unroll
      for (int dk = 0; dk < 2; ++dk) {
        bf16x8 kf = *reinterpret_cast<const bf16x8*>(
            &k[(size_t)(kb * 32 + nt * 16 + lr) * 320 + kvh * 64 + dk * 32 + lg * 8]);
        s[nt] = __builtin_amdgcn_mfma_f32_16x16x32_bf16(qf[dk], kf, s[nt], 0, 0, 0);
      }
#pragma unroll
    for (int nt = 0; nt < 2; ++nt) {
      const int col = kb * 32 + nt * 16 + lr;
#pragma unroll
      for (int r = 0; r < 4; ++r) {
        const int rowi = qrow0 + lg * 4 + r;
        float sv = s[nt][r] * 0.125f;
        s[nt][r] = (col > rowi) ? -1e30f : sv;
      }
    }
    float tm[4], ef[4], ts[4];
#pragma unroll
    for (int r = 0; r < 4; ++r) tm[r] = fmaxf(s[0][r], s[1][r]);
#pragma unroll
    for (int msk = 1; msk <= 8; msk <<= 1)
#pragma unroll
      for (int r = 0; r < 4; ++r) tm[r] = fmaxf(tm[r], __shfl_xor(tm[r], msk));
#pragma unroll
    for (int r = 0; r < 4; ++r) {
      float mn = fmaxf(mrun[r], tm[r]);
      ef[r] = __expf(mrun[r] - mn);
      mrun[r] = mn;
      ts[r] = 0.f;
    }
#pragma unroll
    for (int nt = 0; nt < 2; ++nt)
#pragma unroll
      for (int r = 0; r < 4; ++r) {
        float p = __expf(s[nt][r] - mrun[r]);
        s[nt][r] = p;
        ts[r] += p;
      }
#pragma unroll
    for (int msk = 1; msk <= 8; msk <<= 1)
#pragma unroll
      for (int r = 0; r < 4; ++r) ts[r] += __shfl_xor(ts[r], msk);
#pragma unroll
    for (int r = 0; r < 4; ++r) lrun[r] = lrun[r] * ef[r] + ts[r];
#pragma unroll
    for (int nt2 = 0; nt2 < 4; ++nt2)
#pragma unroll
      for (int r = 0; r < 4; ++r) acc[nt2][r] *= ef[r];
#pragma unroll
    for (int nt = 0; nt < 2; ++nt)
#pragma unroll
      for (int r = 0; r < 4; ++r)
        p_lds[w][lg * 4 + r][nt * 16 + lr] = __float2bfloat16(s[nt][r]);
    bf16x8 pf = *reinterpret_cast<const bf16x8*>(&p_lds[w][lr][lg * 8]);
#pragma unroll
    for (int nt2 = 0; nt2 < 4; ++nt2) {
      bf16x8 vf = *reinterpret_cast<const bf16x8*>(
          &vT[(size_t)(kvh * 64 + nt2 * 16 + lr) * 2048 + kb * 32 + lg * 8]);
      acc[nt2] = __builtin_amdgcn_mfma_f32_16x16x32_bf16(pf, vf, acc[nt2], 0, 0, 0);
    }
  }
  // write partials (no division)
  const size_t base = (((size_t)head * 128 + qt) * 4 + c) * (16 * 64);
#pragma unroll
  for (int nt2 = 0; nt2 < 4; ++nt2)
#pragma unroll
    for (int r = 0; r < 4; ++r)
      pacc[base + (size_t)(lg * 4 + r) * 64 + nt2 * 16 + lr] = acc[nt2][r];
  const size_t mb = (((size_t)head * 128 + qt) * 4 + c) * 32;
  if (lr == 0) {
#pragma unroll
    for (int r = 0; r < 4; ++r) {
      pml[mb + (lg * 4 + r) * 2] = mrun[r];
      pml[mb + (lg * 4 + r) * 2 + 1] = lrun[r];
    }
  }
}

// ---------------- attention merge: combine <=4 chunks -----------------------
// grid (128 qt, 15 head), 256 threads; 16 rows x 64 cols
__launch_bounds__(256)
__global__ void attn_merge_k(const float* __restrict__ pacc, const float* __restrict__ pml,
                             bf16* __restrict__ ctx) {
  const int qt = blockIdx.x, head = blockIdx.y;
  const int nchunks = qt / 32 + 1;
  const size_t base = (((size_t)head * 128 + qt) * 4) * (16 * 64);
  const size_t mb = (((size_t)head * 128 + qt) * 4) * 32;
  for (int i = threadIdx.x; i < 1024; i += 256) {
    const int row = i >> 6, col = i & 63;
    float m = -1e30f;
    for (int c = 0; c < nchunks; ++c) m = fmaxf(m, pml[mb + c * 32 + row * 2]);
    float lsum = 0.f, a = 0.f;
    for (int c = 0; c < nchunks; ++c) {
      float e = __expf(pml[mb + c * 32 + row * 2] - m);
      lsum += pml[mb + c * 32 + row * 2 + 1] * e;
      a += pacc[base + c * 1024 + row * 64 + col] * e;
    }
    ctx[(size_t)(qt * 16 + row) * 960 + head * 64 + col] = __float2bfloat16(a / lsum);
  }
}

// ---------------- SwiGLU activation ----------------------------------------
__launch_bounds__(256)
__global__ void act_k(const bf16* __restrict__ gu, bf16* __restrict__ act) {
  const int i = blockIdx.x * 256 + threadIdx.x;
  if (i >= 2048 * 320) return;
  const int row = i / 320, col = (i % 320) * 8;
  union { bf16x8 v; unsigned short u[8]; } g_, u_, o_;
  g_.v = *reinterpret_cast<const bf16x8*>(&gu[(size_t)row * 5120 + col]);
  u_.v = *reinterpret_cast<const bf16x8*>(&gu[(size_t)row * 5120 + 2560 + col]);
#pragma unroll
  for (int j = 0; j < 8; ++j) {
    float gf = bfu2f(g_.u[j]), uf = bfu2f(u_.u[j]);
    float s = gf / (1.f + __expf(-gf));
    o_.u[j] = f2bfu(s * uf);
  }
  *reinterpret_cast<bf16x8*>(&act[(size_t)row * 2560 + col]) = o_.v;
}

// ---------------- launch ----------------------------------------------------
extern "C" void kernel_launch(void* const* d_in, const int* in_sizes, int n_in,
                              void* d_out, int out_size, void* d_ws, size_t ws_size,
                              hipStream_t stream) {
  const float* x  = (const float*)d_in[0];
  const float* wq = (const float*)d_in[1];
  const float* wk = (const float*)d_in[2];
  const float* wv = (const float*)d_in[3];
  const float* wo = (const float*)d_in[4];
  const float* wg = (const float*)d_in[5];
  const float* wu = (const float*)d_in[6];
  const float* wd = (const float*)d_in[7];
  const float* g1 = (const float*)d_in[8];
  const float* g2 = (const float*)d_in[9];
  float* out = (float*)d_out;

  char* ws = (char*)d_ws;
  // layout (bytes):
  bf16*   wT   = (bf16*)ws;                        // 0 .. 19,660,800
  float*  pacc = (float*)(ws + 19660800);          // 31,457,280 (attn partial acc)
  float*  pml  = (float*)(ws + 51118080);          // 983,040    (attn partial m,l)
  bf16*   hbuf = (bf16*)(ws + 52101120);           // 3,932,160
  bf16*   qr   = (bf16*)(ws + 56033280);           // 3,932,160
  bf16*   kr   = (bf16*)(ws + 59965440);           // 1,310,720
  bf16*   vT   = (bf16*)(ws + 61276160);           // 1,310,720
  bf16*   ctx  = (bf16*)(ws + 62586880);           // 3,932,160
  float*  x2   = (float*)(ws + 66519040);          // 7,864,320
  float2* cst  = (float2*)(ws + 74383360);         // 524,288  (ends 74,907,648)
  bf16*   gu   = (bf16*)(ws + 19660800);           // reuse pacc region after merge
  bf16*   actb = (bf16*)(ws + 40632320);           // 10,485,760 (still in pacc region)

  bf16* wqkvT = wT;           // rows 0..1599: wq(960) | wk(320) | wv(320), K=960
  bf16* wkT = wT + 921600;
  bf16* woT = wT + 1536000;   // 960x960
  bf16* wgT = wT + 2457600;   // 2560x960, wuT contiguous -> 5120x960
  bf16* wuT = wT + 4915200;
  bf16* wdT = wT + 7372800;   // 960x2560

  dim3 blk(256);
  transpose_bf16_k<<<dim3(15, 15), blk, 0, stream>>>(wq, wqkvT, 960, 960);
  transpose_bf16_k<<<dim3(5, 15), blk, 0, stream>>>(wk, wkT, 960, 320);
  transpose_bf16_k<<<dim3(5, 15), blk, 0, stream>>>(wv, wT + 1228800, 960, 320);
  transpose_bf16_k<<<dim3(15, 15), blk, 0, stream>>>(wo, woT, 960, 960);
  transpose_bf16_k<<<dim3(40, 15), blk, 0, stream>>>(wg, wgT, 960, 2560);
  transpose_bf16_k<<<dim3(40, 15), blk, 0, stream>>>(wu, wuT, 960, 2560);
  transpose_bf16_k<<<dim3(15, 40), blk, 0, stream>>>(wd, wdT, 2560, 960);
  rope_tab_k<<<256, blk, 0, stream>>>(cst);

  rmsnorm_k<<<2048, blk, 0, stream>>>(x, g1, hbuf);
  gemm_qkv<<<dim3(13, 16), blk, 0, stream>>>(hbuf, wqkvT, cst, qr, kr, vT);
  attn_part_k<<<dim3(32, 15, 4), blk, 0, stream>>>(qr, kr, vT, pacc, pml);
  attn_merge_k<<<dim3(128, 15), blk, 0, stream>>>(pacc, pml, ctx);
  gemm_bt64<2><<<dim3(8, 32), blk, 0, stream>>>(ctx, woT, x, x2, 960, 960);
  rmsnorm_k<<<2048, blk, 0, stream>>>(x2, g2, hbuf);
  gemm_bt<1><<<dim3(40, 16), blk, 0, stream>>>(hbuf, wgT, nullptr, nullptr, gu, 5120, 960);
  act_k<<<2560, blk, 0, stream>>>(gu, actb);
  gemm_bt64<2><<<dim3(8, 32), blk, 0, stream>>>(actb, wdT, x2, out, 960, 2560);
  rmsnorm_k<<<2048, blk, 0, stream>>>(x2, g1, hbuf);
  gemm_bt64<3><<<dim3(5, 32), blk, 0, stream>>>(hbuf, wkT, nullptr, out + 1966080, 640, 960);
}

// Round 3
// 249.841 us; speedup vs baseline: 1.3412x; 1.2679x over previous
//
#include <hip/hip_runtime.h>
#include <hip/hip_bf16.h>

// TextEncoderBlock R2: swapped-QK^T 32x32 flash attention (lane-local softmax,
// T12 cvt_pk+xor32 P-fragment build, no LDS), SwiGLU fused into FFN GEMM via
// interleaved wg/wu transpose, 64-row qkv GEMM tiles.
// B=1 L=2048 EMBD=960 FFN=2560 QH=15 KVH=5 HD=64

typedef __hip_bfloat16 bf16;
typedef __attribute__((ext_vector_type(8))) short bf16x8;
typedef __attribute__((ext_vector_type(4))) float f32x4;
typedef __attribute__((ext_vector_type(16))) float f32x16;

#define EPS 1.1920929e-07f

__device__ __forceinline__ void gload_lds16(const bf16* g, bf16* l) {
  __builtin_amdgcn_global_load_lds(
      (const __attribute__((address_space(1))) unsigned int*)g,
      (__attribute__((address_space(3))) unsigned int*)l, 16, 0, 0);
}

__device__ __forceinline__ unsigned short f2bfu(float f) {
  __hip_bfloat16 b = __float2bfloat16(f);
  return *reinterpret_cast<unsigned short*>(&b);
}
__device__ __forceinline__ float bfu2f(unsigned short u) {
  return __uint_as_float(((unsigned int)u) << 16);
}
__device__ __forceinline__ unsigned int cvtpk(float lo, float hi_) {
  unsigned int r;
  asm("v_cvt_pk_bf16_f32 %0, %1, %2" : "=v"(r) : "v"(lo), "v"(hi_));
  return r;
}

// ---------------- weight transpose: W (K x N fp32) -> WT (N x K bf16) -------
// MAP 0: identity row. MAP 1/2: 16-col interleave for gate/up fusion.
template <int MAP>
__launch_bounds__(256)
__global__ void transpose_bf16_k(const float* __restrict__ W, bf16* __restrict__ WT,
                                 int K, int N) {
  __shared__ float tile[64][65];
  const int k0 = blockIdx.y * 64, n0 = blockIdx.x * 64;
  const int tx = threadIdx.x & 63, ty = threadIdx.x >> 6;
#pragma unroll
  for (int i = 0; i < 16; ++i) {
    int r = ty + i * 4;
    tile[r][tx] = W[(size_t)(k0 + r) * N + n0 + tx];
  }
  __syncthreads();
#pragma unroll
  for (int i = 0; i < 16; ++i) {
    int r = ty + i * 4;
    int v = n0 + r;
    int row = (MAP == 0) ? v : ((v >> 4) << 5) + (v & 15) + (MAP == 2 ? 16 : 0);
    WT[(size_t)row * K + k0 + tx] = __float2bfloat16(tile[tx][r]);
  }
}

// ---------------- cos/sin table: cstab[pos][d] = (cos, sin), d=0..31 --------
__launch_bounds__(256)
__global__ void rope_tab_k(float2* __restrict__ cstab) {
  const int idx = blockIdx.x * 256 + threadIdx.x;
  if (idx >= 2048 * 32) return;
  const int pos = idx >> 5, d = idx & 31;
  float inv = powf(10000.f, -(float)d * (1.f / 32.f));
  float rad = (float)pos * inv;
  cstab[idx] = make_float2(cosf(rad), sinf(rad));
}

// ---------------- rmsnorm: x (2048 x 960 fp32) -> out bf16 ------------------
__launch_bounds__(256)
__global__ void rmsnorm_k(const float* __restrict__ x, const float* __restrict__ g,
                          bf16* __restrict__ out) {
  const int row = blockIdx.x;
  const float* xr = x + (size_t)row * 960;
  const int t = threadIdx.x;
  float4 v = {0.f, 0.f, 0.f, 0.f};
  float ss = 0.f;
  if (t < 240) {
    v = *reinterpret_cast<const float4*>(&xr[t * 4]);
    ss = v.x * v.x + v.y * v.y + v.z * v.z + v.w * v.w;
  }
#pragma unroll
  for (int off = 32; off; off >>= 1) ss += __shfl_down(ss, off);
  __shared__ float red[4];
  __shared__ float s_scale;
  if ((t & 63) == 0) red[t >> 6] = ss;
  __syncthreads();
  if (t == 0) {
    float tot = red[0] + red[1] + red[2] + red[3];
    s_scale = rsqrtf(tot * (1.f / 960.f) + EPS);
  }
  __syncthreads();
  if (t < 240) {
    const float sc = s_scale;
    const float4 gv = *reinterpret_cast<const float4*>(&g[t * 4]);
    ushort4 o;
    o.x = f2bfu(v.x * sc * gv.x);
    o.y = f2bfu(v.y * sc * gv.y);
    o.z = f2bfu(v.z * sc * gv.z);
    o.w = f2bfu(v.w * sc * gv.w);
    *reinterpret_cast<ushort4*>(&out[(size_t)row * 960 + t * 4]) = o;
  }
}

// ---------------- FFN GEMM 128x128, fused SwiGLU epilogue -------------------
// BT = interleaved [gate16 | up16] blocks, 5120 rows. Output actb 2048x2560.
__launch_bounds__(256)
__global__ void gemm_ffn(const bf16* __restrict__ A, const bf16* __restrict__ BT,
                         bf16* __restrict__ actb) {
  const int N = 5120, K = 960;
  __shared__ __align__(16) bf16 sA[2][128 * 32];
  __shared__ __align__(16) bf16 sB[2][128 * 32];
  const int t = threadIdx.x, w = t >> 6, lane = t & 63;
  const int lg = lane >> 4, lr = lane & 15;
  const int wm = w >> 1, wn = w & 1;
  const int m0 = blockIdx.y * 128, n0 = blockIdx.x * 128;
  f32x4 acc[4][4] = {};
  const int nsteps = K / 32;

  auto stage = [&](int buf, int ks) {
    const int k0 = ks * 32;
#pragma unroll
    for (int i = 0; i < 2; ++i) {
      int c = w * 128 + i * 64 + lane;
      int r = c >> 2, kc = (c & 3) * 8;
      gload_lds16(A + (size_t)(m0 + r) * K + k0 + kc, &sA[buf][c * 8]);
      gload_lds16(BT + (size_t)(n0 + r) * K + k0 + kc, &sB[buf][c * 8]);
    }
  };

  stage(0, 0);
  __syncthreads();
  int cur = 0;
  for (int ks = 0; ks < nsteps; ++ks) {
    if (ks + 1 < nsteps) stage(cur ^ 1, ks + 1);
    bf16x8 af[4], bfr[4];
#pragma unroll
    for (int mi = 0; mi < 4; ++mi)
      af[mi] = *reinterpret_cast<const bf16x8*>(&sA[cur][(wm * 64 + mi * 16 + lr) * 32 + lg * 8]);
#pragma unroll
    for (int ni = 0; ni < 4; ++ni)
      bfr[ni] = *reinterpret_cast<const bf16x8*>(&sB[cur][(wn * 64 + ni * 16 + lr) * 32 + lg * 8]);
#pragma unroll
    for (int mi = 0; mi < 4; ++mi)
#pragma unroll
      for (int ni = 0; ni < 4; ++ni)
        acc[mi][ni] = __builtin_amdgcn_mfma_f32_16x16x32_bf16(af[mi], bfr[ni], acc[mi][ni], 0, 0, 0);
    __syncthreads();
    cur ^= 1;
  }

  const int colbase = n0 + wn * 64;
#pragma unroll
  for (int mi = 0; mi < 4; ++mi) {
    const int row = m0 + wm * 64 + mi * 16 + lg * 4;
#pragma unroll
    for (int p = 0; p < 2; ++p) {
      const int oc = ((colbase >> 5) + p) * 16 + lr;
#pragma unroll
      for (int r = 0; r < 4; ++r) {
        float gf = acc[mi][2 * p][r], uf = acc[mi][2 * p + 1][r];
        float s = gf / (1.f + __expf(-gf));
        actb[(size_t)(row + r) * 2560 + oc] = __float2bfloat16(s * uf);
      }
    }
  }
}

// ---------------- GEMM 64x128 (small N): MODE 2 += Res, MODE 3 split kv -----
template <int MODE>
__launch_bounds__(256)
__global__ void gemm_bt64(const bf16* __restrict__ A, const bf16* __restrict__ BT,
                          const float* __restrict__ Res, float* __restrict__ Cf,
                          int N, int K) {
  __shared__ __align__(16) bf16 sA[2][64 * 32];
  __shared__ __align__(16) bf16 sB[2][128 * 32];
  const int t = threadIdx.x, w = t >> 6, lane = t & 63;
  const int lg = lane >> 4, lr = lane & 15;
  const int wm = w >> 1, wn = w & 1;
  const int m0 = blockIdx.y * 64, n0 = blockIdx.x * 128;
  f32x4 acc[2][4] = {};
  const int nsteps = K / 32;

  auto stage = [&](int buf, int ks) {
    const int k0 = ks * 32;
    {
      int c = t;
      int r = c >> 2, kc = (c & 3) * 8;
      gload_lds16(A + (size_t)(m0 + r) * K + k0 + kc, &sA[buf][c * 8]);
    }
#pragma unroll
    for (int i = 0; i < 2; ++i) {
      int c = i * 256 + t;
      int r = c >> 2, kc = (c & 3) * 8;
      int br = n0 + r;
      if (br >= N) br = N - 1;
      gload_lds16(BT + (size_t)br * K + k0 + kc, &sB[buf][c * 8]);
    }
  };

  stage(0, 0);
  __syncthreads();
  int cur = 0;
  for (int ks = 0; ks < nsteps; ++ks) {
    if (ks + 1 < nsteps) stage(cur ^ 1, ks + 1);
    bf16x8 af[2], bfr[4];
#pragma unroll
    for (int mi = 0; mi < 2; ++mi)
      af[mi] = *reinterpret_cast<const bf16x8*>(&sA[cur][(wm * 32 + mi * 16 + lr) * 32 + lg * 8]);
#pragma unroll
    for (int ni = 0; ni < 4; ++ni)
      bfr[ni] = *reinterpret_cast<const bf16x8*>(&sB[cur][(wn * 64 + ni * 16 + lr) * 32 + lg * 8]);
#pragma unroll
    for (int mi = 0; mi < 2; ++mi)
#pragma unroll
      for (int ni = 0; ni < 4; ++ni)
        acc[mi][ni] = __builtin_amdgcn_mfma_f32_16x16x32_bf16(af[mi], bfr[ni], acc[mi][ni], 0, 0, 0);
    __syncthreads();
    cur ^= 1;
  }

#pragma unroll
  for (int mi = 0; mi < 2; ++mi) {
    const int row = m0 + wm * 32 + mi * 16 + lg * 4;
#pragma unroll
    for (int ni = 0; ni < 4; ++ni) {
      const int col = n0 + wn * 64 + ni * 16 + lr;
      if (col < N) {
#pragma unroll
        for (int r = 0; r < 4; ++r) {
          float v = acc[mi][ni][r];
          size_t idx = (size_t)(row + r) * N + col;
          if (MODE == 2) {
            Cf[idx] = v + Res[idx];
          } else {  // MODE 3: N=640 -> k_out | v_out
            int rr = row + r;
            if (col < 320)
              Cf[(size_t)rr * 320 + col] = v;
            else
              Cf[655360 + (size_t)rr * 320 + (col - 320)] = v;
          }
        }
      }
    }
  }
}

// ---------------- QKV GEMM 64x128 with fused RoPE + V-transpose epilogue ----
// N=1600 (q 0..959 | k 960..1279 | v 1280..1599), K=960
__launch_bounds__(256)
__global__ void gemm_qkv(const bf16* __restrict__ A, const bf16* __restrict__ BT,
                         const float2* __restrict__ cstab, bf16* __restrict__ qr,
                         bf16* __restrict__ kr, bf16* __restrict__ vT) {
  const int N = 1600, K = 960;
  __shared__ __align__(16) bf16 sA[2][64 * 32];
  __shared__ __align__(16) bf16 sB[2][128 * 32];
  const int t = threadIdx.x, w = t >> 6, lane = t & 63;
  const int lg = lane >> 4, lr = lane & 15;
  const int wm = w >> 1, wn = w & 1;
  const int m0 = blockIdx.y * 64, n0 = blockIdx.x * 128;
  f32x4 acc[2][4] = {};
  const int nsteps = K / 32;

  auto stage = [&](int buf, int ks) {
    const int k0 = ks * 32;
    {
      int c = t;
      int r = c >> 2, kc = (c & 3) * 8;
      gload_lds16(A + (size_t)(m0 + r) * K + k0 + kc, &sA[buf][c * 8]);
    }
#pragma unroll
    for (int i = 0; i < 2; ++i) {
      int c = i * 256 + t;
      int r = c >> 2, kc = (c & 3) * 8;
      int br = n0 + r;
      if (br >= N) br = N - 1;
      gload_lds16(BT + (size_t)br * K + k0 + kc, &sB[buf][c * 8]);
    }
  };

  stage(0, 0);
  __syncthreads();
  int cur = 0;
  for (int ks = 0; ks < nsteps; ++ks) {
    if (ks + 1 < nsteps) stage(cur ^ 1, ks + 1);
    bf16x8 af[2], bfr[4];
#pragma unroll
    for (int mi = 0; mi < 2; ++mi)
      af[mi] = *reinterpret_cast<const bf16x8*>(&sA[cur][(wm * 32 + mi * 16 + lr) * 32 + lg * 8]);
#pragma unroll
    for (int ni = 0; ni < 4; ++ni)
      bfr[ni] = *reinterpret_cast<const bf16x8*>(&sB[cur][(wn * 64 + ni * 16 + lr) * 32 + lg * 8]);
#pragma unroll
    for (int mi = 0; mi < 2; ++mi)
#pragma unroll
      for (int ni = 0; ni < 4; ++ni)
        acc[mi][ni] = __builtin_amdgcn_mfma_f32_16x16x32_bf16(af[mi], bfr[ni], acc[mi][ni], 0, 0, 0);
    __syncthreads();
    cur ^= 1;
  }

  const int colbase = n0 + wn * 64;
  if (colbase >= 1600) return;
  if (colbase < 1280) {
    const bool isq = colbase < 960;
    bf16* dst = isq ? qr : kr;
    const int ncols = isq ? 960 : 320;
    const int cb = isq ? colbase : colbase - 960;
#pragma unroll
    for (int mi = 0; mi < 2; ++mi) {
      const int row = m0 + wm * 32 + mi * 16 + lg * 4;
#pragma unroll
      for (int ni = 0; ni < 2; ++ni) {
        const int d = ni * 16 + lr;
#pragma unroll
        for (int r = 0; r < 4; ++r) {
          const int pos = row + r;
          float2 cs = cstab[pos * 32 + d];
          float x1 = acc[mi][ni][r], x2 = acc[mi][ni + 2][r];
          dst[(size_t)pos * ncols + cb + d] = __float2bfloat16(x1 * cs.x - x2 * cs.y);
          dst[(size_t)pos * ncols + cb + d + 32] = __float2bfloat16(x2 * cs.x + x1 * cs.y);
        }
      }
    }
  } else {
#pragma unroll
    for (int mi = 0; mi < 2; ++mi) {
      const int row = m0 + wm * 32 + mi * 16 + lg * 4;
#pragma unroll
      for (int ni = 0; ni < 4; ++ni) {
        const int vc = colbase - 1280 + ni * 16 + lr;
        ushort4 pk;
        pk.x = f2bfu(acc[mi][ni][0]);
        pk.y = f2bfu(acc[mi][ni][1]);
        pk.z = f2bfu(acc[mi][ni][2]);
        pk.w = f2bfu(acc[mi][ni][3]);
        *reinterpret_cast<ushort4*>(&vT[(size_t)vc * 2048 + row]) = pk;
      }
    }
  }
}

// ---------------- swapped-QK^T flash attention (32x32 MFMA, 1 wave/block) ---
// grid (64 qt, 15 head, 4 chunk), block 64. Wave computes S^T = K·Q^T so each
// lane owns softmax state for q = q0 + (lane&31); kv rows live in 16 regs.
__launch_bounds__(64)
__global__ void attn_part2(const bf16* __restrict__ q, const bf16* __restrict__ k,
                           const bf16* __restrict__ vT, float* __restrict__ pacc,
                           float* __restrict__ pml) {
  const int qt = blockIdx.x, head = blockIdx.y, c = blockIdx.z;
  if (c * 16 > qt) return;
  const int lane = threadIdx.x & 63;
  const int ql = lane & 31;          // q column owned by this lane
  const int hi = lane >> 5;          // upper-half flag
  const int q0 = qt * 32;
  const int kvh = head / 3;
  const int t0 = c * 16, t1 = min(t0 + 16, qt + 1);

  // Q fragments: B-operand, col = ql, k = hi*8+j, 4 chunks of d
  bf16x8 qf[4];
#pragma unroll
  for (int i = 0; i < 4; ++i)
    qf[i] = *reinterpret_cast<const bf16x8*>(
        &q[(size_t)(q0 + ql) * 960 + head * 64 + i * 16 + hi * 8]);

  f32x16 acc0 = {}, acc1 = {};
  float mrun = -1e30f, lrun = 0.f;
  const int qrow = q0 + ql;
  const int kvoff = 4 * hi;

  for (int kb = t0; kb < t1; ++kb) {
    // ---- S^T = K · Q^T  (rows kv, cols q) ----
    f32x16 s = {};
#pragma unroll
    for (int i = 0; i < 4; ++i) {
      bf16x8 kf = *reinterpret_cast<const bf16x8*>(
          &k[(size_t)(kb * 32 + ql) * 320 + kvh * 64 + i * 16 + hi * 8]);
      s = __builtin_amdgcn_mfma_f32_32x32x16_bf16(kf, qf[i], s, 0, 0, 0);
    }
    // scale + causal mask (diagonal tile only)
    if (kb == qt) {
      const int kvb = kb * 32 + kvoff;
#pragma unroll
      for (int r = 0; r < 16; ++r) {
        const int kv = kvb + (r & 3) + 8 * (r >> 2);
        float sv = s[r] * 0.125f;
        s[r] = (kv > qrow) ? -1e30f : sv;
      }
    } else {
#pragma unroll
      for (int r = 0; r < 16; ++r) s[r] *= 0.125f;
    }
    // ---- lane-local softmax (one cross-lane hop) ----
    float tm = s[0];
#pragma unroll
    for (int r = 1; r < 16; ++r) tm = fmaxf(tm, s[r]);
    tm = fmaxf(tm, __shfl_xor(tm, 32));
    const float mn = fmaxf(mrun, tm);
    const float ef = __expf(mrun - mn);
    mrun = mn;
    float ts = 0.f;
#pragma unroll
    for (int r = 0; r < 16; ++r) {
      float p = __expf(s[r] - mn);
      s[r] = p;
      ts += p;
    }
    ts += __shfl_xor(ts, 32);
    lrun = lrun * ef + ts;
#pragma unroll
    for (int r = 0; r < 16; ++r) { acc0[r] *= ef; acc1[r] *= ef; }
    // ---- P^T -> bf16 B-fragments (cvt_pk + xor32 exchange) ----
    unsigned int a0 = cvtpk(s[0], s[1]), a1 = cvtpk(s[2], s[3]);
    unsigned int a2 = cvtpk(s[4], s[5]), a3 = cvtpk(s[6], s[7]);
    unsigned int b0 = cvtpk(s[8], s[9]), b1 = cvtpk(s[10], s[11]);
    unsigned int b2 = cvtpk(s[12], s[13]), b3 = cvtpk(s[14], s[15]);
    unsigned int x0 = __shfl_xor(a0, 32), x1 = __shfl_xor(a1, 32);
    unsigned int x2 = __shfl_xor(a2, 32), x3 = __shfl_xor(a3, 32);
    unsigned int y0 = __shfl_xor(b0, 32), y1 = __shfl_xor(b1, 32);
    unsigned int y2 = __shfl_xor(b2, 32), y3 = __shfl_xor(b3, 32);
    union { unsigned int u[4]; bf16x8 v; } f0, f1;
    f0.u[0] = hi ? x2 : a0; f0.u[1] = hi ? x3 : a1;
    f0.u[2] = hi ? a2 : x0; f0.u[3] = hi ? a3 : x1;
    f1.u[0] = hi ? y2 : b0; f1.u[1] = hi ? y3 : b1;
    f1.u[2] = hi ? b2 : y0; f1.u[3] = hi ? b3 : y1;
    // ---- O^T += V^T · P^T ----
    const size_t vbase = (size_t)(kvh * 64 + ql) * 2048 + kb * 32 + hi * 8;
    bf16x8 v00 = *reinterpret_cast<const bf16x8*>(&vT[vbase]);
    bf16x8 v01 = *reinterpret_cast<const bf16x8*>(&vT[vbase + 16]);
    bf16x8 v10 = *reinterpret_cast<const bf16x8*>(&vT[vbase + 32 * 2048]);
    bf16x8 v11 = *reinterpret_cast<const bf16x8*>(&vT[vbase + 32 * 2048 + 16]);
    acc0 = __builtin_amdgcn_mfma_f32_32x32x16_bf16(v00, f0.v, acc0, 0, 0, 0);
    acc0 = __builtin_amdgcn_mfma_f32_32x32x16_bf16(v01, f1.v, acc0, 0, 0, 0);
    acc1 = __builtin_amdgcn_mfma_f32_32x32x16_bf16(v10, f0.v, acc1, 0, 0, 0);
    acc1 = __builtin_amdgcn_mfma_f32_32x32x16_bf16(v11, f1.v, acc1, 0, 0, 0);
  }

  // ---- write partials: pacc[job][d=64][q=32], pml[job][q][2] ----
  const size_t base = (((size_t)head * 64 + qt) * 4 + c) * 2048;
#pragma unroll
  for (int r = 0; r < 16; ++r) {
    const int row = (r & 3) + 8 * (r >> 2) + kvoff;  // d-local 0..31
    pacc[base + (size_t)row * 32 + ql] = acc0[r];
    pacc[base + (size_t)(row + 32) * 32 + ql] = acc1[r];
  }
  const size_t mb = (((size_t)head * 64 + qt) * 4 + c) * 64;
  if (!hi) {
    pacc += 0;  // no-op
    pml[mb + ql * 2] = mrun;
    pml[mb + ql * 2 + 1] = lrun;
  }
}

// ---------------- attention merge: combine <=4 chunks -----------------------
// grid (64 qt, 15 head), 256 threads; output 32 q-rows x 64 d
__launch_bounds__(256)
__global__ void attn_merge2(const float* __restrict__ pacc, const float* __restrict__ pml,
                            bf16* __restrict__ ctx) {
  const int qt = blockIdx.x, head = blockIdx.y;
  const int nch = qt / 16 + 1;
  const size_t base = (((size_t)head * 64 + qt) * 4) * 2048;
  const size_t mb = (((size_t)head * 64 + qt) * 4) * 64;
  for (int i = threadIdx.x; i < 2048; i += 256) {
    const int qi = i >> 6, d = i & 63;
    float m = -1e30f;
    for (int c = 0; c < nch; ++c) m = fmaxf(m, pml[mb + c * 64 + qi * 2]);
    float lsum = 0.f, o = 0.f;
    for (int c = 0; c < nch; ++c) {
      float e = __expf(pml[mb + c * 64 + qi * 2] - m);
      lsum += pml[mb + c * 64 + qi * 2 + 1] * e;
      o += pacc[base + c * 2048 + d * 32 + qi] * e;
    }
    ctx[(size_t)(qt * 32 + qi) * 960 + head * 64 + d] = __float2bfloat16(o / lsum);
  }
}

// ---------------- launch ----------------------------------------------------
extern "C" void kernel_launch(void* const* d_in, const int* in_sizes, int n_in,
                              void* d_out, int out_size, void* d_ws, size_t ws_size,
                              hipStream_t stream) {
  const float* x  = (const float*)d_in[0];
  const float* wq = (const float*)d_in[1];
  const float* wk = (const float*)d_in[2];
  const float* wv = (const float*)d_in[3];
  const float* wo = (const float*)d_in[4];
  const float* wg = (const float*)d_in[5];
  const float* wu = (const float*)d_in[6];
  const float* wd = (const float*)d_in[7];
  const float* g1 = (const float*)d_in[8];
  const float* g2 = (const float*)d_in[9];
  float* out = (float*)d_out;

  char* ws = (char*)d_ws;
  bf16*   wT   = (bf16*)ws;                        // 0 .. 19,660,800 bytes
  float*  pacc = (float*)(ws + 19660800);          // 31,457,280 (attn partials)
  float*  pml  = (float*)(ws + 51118080);          // 983,040
  bf16*   hbuf = (bf16*)(ws + 52101120);           // 3,932,160
  bf16*   qr   = (bf16*)(ws + 56033280);           // 3,932,160
  bf16*   kr   = (bf16*)(ws + 59965440);           // 1,310,720
  bf16*   vT   = (bf16*)(ws + 61276160);           // 1,310,720
  bf16*   ctx  = (bf16*)(ws + 62586880);           // 3,932,160
  float*  x2   = (float*)(ws + 66519040);          // 7,864,320
  float2* cst  = (float2*)(ws + 74383360);         // 524,288
  bf16*   actb = (bf16*)(ws + 19660800);           // reuse pacc region (10.5MB)

  bf16* wqkvT = wT;           // 1600 rows x K=960: wq | wk | wv
  bf16* wkT  = wT + 921600;   // (k rows within wqkvT)
  bf16* woT  = wT + 1536000;  // 960x960
  bf16* wguT = wT + 2457600;  // 5120x960 interleaved [gate16|up16]
  bf16* wdT  = wT + 7372800;  // 960x2560

  dim3 blk(256);
  transpose_bf16_k<0><<<dim3(15, 15), blk, 0, stream>>>(wq, wqkvT, 960, 960);
  transpose_bf16_k<0><<<dim3(5, 15), blk, 0, stream>>>(wk, wkT, 960, 320);
  transpose_bf16_k<0><<<dim3(5, 15), blk, 0, stream>>>(wv, wT + 1228800, 960, 320);
  transpose_bf16_k<0><<<dim3(15, 15), blk, 0, stream>>>(wo, woT, 960, 960);
  transpose_bf16_k<1><<<dim3(40, 15), blk, 0, stream>>>(wg, wguT, 960, 2560);
  transpose_bf16_k<2><<<dim3(40, 15), blk, 0, stream>>>(wu, wguT, 960, 2560);
  transpose_bf16_k<0><<<dim3(15, 40), blk, 0, stream>>>(wd, wdT, 2560, 960);
  rope_tab_k<<<256, blk, 0, stream>>>(cst);

  rmsnorm_k<<<2048, blk, 0, stream>>>(x, g1, hbuf);
  gemm_qkv<<<dim3(13, 32), blk, 0, stream>>>(hbuf, wqkvT, cst, qr, kr, vT);
  attn_part2<<<dim3(64, 15, 4), dim3(64), 0, stream>>>(qr, kr, vT, pacc, pml);
  attn_merge2<<<dim3(64, 15), blk, 0, stream>>>(pacc, pml, ctx);
  gemm_bt64<2><<<dim3(8, 32), blk, 0, stream>>>(ctx, woT, x, x2, 960, 960);
  rmsnorm_k<<<2048, blk, 0, stream>>>(x2, g2, hbuf);
  gemm_ffn<<<dim3(40, 16), blk, 0, stream>>>(hbuf, wguT, actb);
  gemm_bt64<2><<<dim3(8, 32), blk, 0, stream>>>(actb, wdT, x2, out, 960, 2560);
  rmsnorm_k<<<2048, blk, 0, stream>>>(x2, g1, hbuf);
  gemm_bt64<3><<<dim3(5, 32), blk, 0, stream>>>(hbuf, wkT, nullptr, out + 1966080, 640, 960);
}

// Round 4
// 235.552 us; speedup vs baseline: 1.4226x; 1.0607x over previous
//
#include <hip/hip_runtime.h>
#include <hip/hip_bf16.h>

// TextEncoderBlock R3: attention KVBLK=64 (dual MFMA chains, V-load overlap),
// all weight-prep fused into one launch. Swapped-QK^T lane-local softmax,
// SwiGLU fused FFN GEMM, RoPE fused QKV epilogue.
// B=1 L=2048 EMBD=960 FFN=2560 QH=15 KVH=5 HD=64

typedef __hip_bfloat16 bf16;
typedef __attribute__((ext_vector_type(8))) short bf16x8;
typedef __attribute__((ext_vector_type(4))) float f32x4;
typedef __attribute__((ext_vector_type(16))) float f32x16;

#define EPS 1.1920929e-07f

__device__ __forceinline__ void gload_lds16(const bf16* g, bf16* l) {
  __builtin_amdgcn_global_load_lds(
      (const __attribute__((address_space(1))) unsigned int*)g,
      (__attribute__((address_space(3))) unsigned int*)l, 16, 0, 0);
}

__device__ __forceinline__ unsigned short f2bfu(float f) {
  __hip_bfloat16 b = __float2bfloat16(f);
  return *reinterpret_cast<unsigned short*>(&b);
}
__device__ __forceinline__ float bfu2f(unsigned short u) {
  return __uint_as_float(((unsigned int)u) << 16);
}
__device__ __forceinline__ unsigned int cvtpk(float lo, float hi_) {
  unsigned int r;
  asm("v_cvt_pk_bf16_f32 %0, %1, %2" : "=v"(r) : "v"(lo), "v"(hi_));
  return r;
}

// ---------------- fused prep: 7 weight transposes + rope table --------------
// W (K x N fp32) -> WT (N x K bf16); MAP 1/2 interleave gate/up 16-col blocks.
__device__ void do_transpose(float (*tile)[65], const float* __restrict__ W,
                             bf16* __restrict__ WT, int K, int N, int bx, int by,
                             int map) {
  const int k0 = by * 64, n0 = bx * 64;
  const int tx = threadIdx.x & 63, ty = threadIdx.x >> 6;
#pragma unroll
  for (int i = 0; i < 16; ++i) {
    int r = ty + i * 4;
    tile[r][tx] = W[(size_t)(k0 + r) * N + n0 + tx];
  }
  __syncthreads();
#pragma unroll
  for (int i = 0; i < 16; ++i) {
    int r = ty + i * 4;
    int v = n0 + r;
    int row = (map == 0) ? v : ((v >> 4) << 5) + (v & 15) + (map == 2 ? 16 : 0);
    WT[(size_t)row * K + k0 + tx] = __float2bfloat16(tile[tx][r]);
  }
}

__launch_bounds__(256)
__global__ void prep_k(const float* __restrict__ wq, const float* __restrict__ wk,
                       const float* __restrict__ wv, const float* __restrict__ wo,
                       const float* __restrict__ wg, const float* __restrict__ wu,
                       const float* __restrict__ wd, bf16* __restrict__ wqkvT,
                       bf16* __restrict__ woT, bf16* __restrict__ wguT,
                       bf16* __restrict__ wdT, float2* __restrict__ cstab) {
  __shared__ float tile[64][65];
  int b = blockIdx.x;
  if (b < 225) {            // wq: 960x960 -> rows 0..959 of wqkvT
    do_transpose(tile, wq, wqkvT, 960, 960, b % 15, b / 15, 0);
  } else if (b < 300) {     // wk: 960x320 -> rows 960..1279
    b -= 225;
    do_transpose(tile, wk, wqkvT + 921600, 960, 320, b % 5, b / 5, 0);
  } else if (b < 375) {     // wv: 960x320 -> rows 1280..1599
    b -= 300;
    do_transpose(tile, wv, wqkvT + 1228800, 960, 320, b % 5, b / 5, 0);
  } else if (b < 600) {     // wo: 960x960
    b -= 375;
    do_transpose(tile, wo, woT, 960, 960, b % 15, b / 15, 0);
  } else if (b < 1200) {    // wg: 960x2560, interleaved slot 0
    b -= 600;
    do_transpose(tile, wg, wguT, 960, 2560, b % 40, b / 40, 1);
  } else if (b < 1800) {    // wu: interleaved slot 1
    b -= 1200;
    do_transpose(tile, wu, wguT, 960, 2560, b % 40, b / 40, 2);
  } else if (b < 2400) {    // wd: 2560x960
    b -= 1800;
    do_transpose(tile, wd, wdT, 2560, 960, b % 15, b / 15, 0);
  } else {                  // rope cos/sin table
    const int idx = (b - 2400) * 256 + threadIdx.x;
    const int pos = idx >> 5, d = idx & 31;
    float inv = powf(10000.f, -(float)d * (1.f / 32.f));
    float rad = (float)pos * inv;
    cstab[idx] = make_float2(cosf(rad), sinf(rad));
  }
}

// ---------------- rmsnorm: x (2048 x 960 fp32) -> out bf16 ------------------
__launch_bounds__(256)
__global__ void rmsnorm_k(const float* __restrict__ x, const float* __restrict__ g,
                          bf16* __restrict__ out) {
  const int row = blockIdx.x;
  const float* xr = x + (size_t)row * 960;
  const int t = threadIdx.x;
  float4 v = {0.f, 0.f, 0.f, 0.f};
  float ss = 0.f;
  if (t < 240) {
    v = *reinterpret_cast<const float4*>(&xr[t * 4]);
    ss = v.x * v.x + v.y * v.y + v.z * v.z + v.w * v.w;
  }
#pragma unroll
  for (int off = 32; off; off >>= 1) ss += __shfl_down(ss, off);
  __shared__ float red[4];
  __shared__ float s_scale;
  if ((t & 63) == 0) red[t >> 6] = ss;
  __syncthreads();
  if (t == 0) {
    float tot = red[0] + red[1] + red[2] + red[3];
    s_scale = rsqrtf(tot * (1.f / 960.f) + EPS);
  }
  __syncthreads();
  if (t < 240) {
    const float sc = s_scale;
    const float4 gv = *reinterpret_cast<const float4*>(&g[t * 4]);
    ushort4 o;
    o.x = f2bfu(v.x * sc * gv.x);
    o.y = f2bfu(v.y * sc * gv.y);
    o.z = f2bfu(v.z * sc * gv.z);
    o.w = f2bfu(v.w * sc * gv.w);
    *reinterpret_cast<ushort4*>(&out[(size_t)row * 960 + t * 4]) = o;
  }
}

// ---------------- FFN GEMM 128x128, fused SwiGLU epilogue -------------------
__launch_bounds__(256)
__global__ void gemm_ffn(const bf16* __restrict__ A, const bf16* __restrict__ BT,
                         bf16* __restrict__ actb) {
  const int K = 960;
  __shared__ __align__(16) bf16 sA[2][128 * 32];
  __shared__ __align__(16) bf16 sB[2][128 * 32];
  const int t = threadIdx.x, w = t >> 6, lane = t & 63;
  const int lg = lane >> 4, lr = lane & 15;
  const int wm = w >> 1, wn = w & 1;
  const int m0 = blockIdx.y * 128, n0 = blockIdx.x * 128;
  f32x4 acc[4][4] = {};
  const int nsteps = K / 32;

  auto stage = [&](int buf, int ks) {
    const int k0 = ks * 32;
#pragma unroll
    for (int i = 0; i < 2; ++i) {
      int c = w * 128 + i * 64 + lane;
      int r = c >> 2, kc = (c & 3) * 8;
      gload_lds16(A + (size_t)(m0 + r) * K + k0 + kc, &sA[buf][c * 8]);
      gload_lds16(BT + (size_t)(n0 + r) * K + k0 + kc, &sB[buf][c * 8]);
    }
  };

  stage(0, 0);
  __syncthreads();
  int cur = 0;
  for (int ks = 0; ks < nsteps; ++ks) {
    if (ks + 1 < nsteps) stage(cur ^ 1, ks + 1);
    bf16x8 af[4], bfr[4];
#pragma unroll
    for (int mi = 0; mi < 4; ++mi)
      af[mi] = *reinterpret_cast<const bf16x8*>(&sA[cur][(wm * 64 + mi * 16 + lr) * 32 + lg * 8]);
#pragma unroll
    for (int ni = 0; ni < 4; ++ni)
      bfr[ni] = *reinterpret_cast<const bf16x8*>(&sB[cur][(wn * 64 + ni * 16 + lr) * 32 + lg * 8]);
#pragma unroll
    for (int mi = 0; mi < 4; ++mi)
#pragma unroll
      for (int ni = 0; ni < 4; ++ni)
        acc[mi][ni] = __builtin_amdgcn_mfma_f32_16x16x32_bf16(af[mi], bfr[ni], acc[mi][ni], 0, 0, 0);
    __syncthreads();
    cur ^= 1;
  }

  const int colbase = n0 + wn * 64;
#pragma unroll
  for (int mi = 0; mi < 4; ++mi) {
    const int row = m0 + wm * 64 + mi * 16 + lg * 4;
#pragma unroll
    for (int p = 0; p < 2; ++p) {
      const int oc = ((colbase >> 5) + p) * 16 + lr;
#pragma unroll
      for (int r = 0; r < 4; ++r) {
        float gf = acc[mi][2 * p][r], uf = acc[mi][2 * p + 1][r];
        float s = gf / (1.f + __expf(-gf));
        actb[(size_t)(row + r) * 2560 + oc] = __float2bfloat16(s * uf);
      }
    }
  }
}

// ---------------- GEMM 64x128 (small N): MODE 2 += Res, MODE 3 split kv -----
template <int MODE>
__launch_bounds__(256)
__global__ void gemm_bt64(const bf16* __restrict__ A, const bf16* __restrict__ BT,
                          const float* __restrict__ Res, float* __restrict__ Cf,
                          int N, int K) {
  __shared__ __align__(16) bf16 sA[2][64 * 32];
  __shared__ __align__(16) bf16 sB[2][128 * 32];
  const int t = threadIdx.x, w = t >> 6, lane = t & 63;
  const int lg = lane >> 4, lr = lane & 15;
  const int wm = w >> 1, wn = w & 1;
  const int m0 = blockIdx.y * 64, n0 = blockIdx.x * 128;
  f32x4 acc[2][4] = {};
  const int nsteps = K / 32;

  auto stage = [&](int buf, int ks) {
    const int k0 = ks * 32;
    {
      int c = t;
      int r = c >> 2, kc = (c & 3) * 8;
      gload_lds16(A + (size_t)(m0 + r) * K + k0 + kc, &sA[buf][c * 8]);
    }
#pragma unroll
    for (int i = 0; i < 2; ++i) {
      int c = i * 256 + t;
      int r = c >> 2, kc = (c & 3) * 8;
      int br = n0 + r;
      if (br >= N) br = N - 1;
      gload_lds16(BT + (size_t)br * K + k0 + kc, &sB[buf][c * 8]);
    }
  };

  stage(0, 0);
  __syncthreads();
  int cur = 0;
  for (int ks = 0; ks < nsteps; ++ks) {
    if (ks + 1 < nsteps) stage(cur ^ 1, ks + 1);
    bf16x8 af[2], bfr[4];
#pragma unroll
    for (int mi = 0; mi < 2; ++mi)
      af[mi] = *reinterpret_cast<const bf16x8*>(&sA[cur][(wm * 32 + mi * 16 + lr) * 32 + lg * 8]);
#pragma unroll
    for (int ni = 0; ni < 4; ++ni)
      bfr[ni] = *reinterpret_cast<const bf16x8*>(&sB[cur][(wn * 64 + ni * 16 + lr) * 32 + lg * 8]);
#pragma unroll
    for (int mi = 0; mi < 2; ++mi)
#pragma unroll
      for (int ni = 0; ni < 4; ++ni)
        acc[mi][ni] = __builtin_amdgcn_mfma_f32_16x16x32_bf16(af[mi], bfr[ni], acc[mi][ni], 0, 0, 0);
    __syncthreads();
    cur ^= 1;
  }

#pragma unroll
  for (int mi = 0; mi < 2; ++mi) {
    const int row = m0 + wm * 32 + mi * 16 + lg * 4;
#pragma unroll
    for (int ni = 0; ni < 4; ++ni) {
      const int col = n0 + wn * 64 + ni * 16 + lr;
      if (col < N) {
#pragma unroll
        for (int r = 0; r < 4; ++r) {
          float v = acc[mi][ni][r];
          size_t idx = (size_t)(row + r) * N + col;
          if (MODE == 2) {
            Cf[idx] = v + Res[idx];
          } else {  // MODE 3: N=640 -> k_out | v_out
            int rr = row + r;
            if (col < 320)
              Cf[(size_t)rr * 320 + col] = v;
            else
              Cf[655360 + (size_t)rr * 320 + (col - 320)] = v;
          }
        }
      }
    }
  }
}

// ---------------- QKV GEMM 64x128 with fused RoPE + V-transpose epilogue ----
__launch_bounds__(256)
__global__ void gemm_qkv(const bf16* __restrict__ A, const bf16* __restrict__ BT,
                         const float2* __restrict__ cstab, bf16* __restrict__ qr,
                         bf16* __restrict__ kr, bf16* __restrict__ vT) {
  const int N = 1600, K = 960;
  __shared__ __align__(16) bf16 sA[2][64 * 32];
  __shared__ __align__(16) bf16 sB[2][128 * 32];
  const int t = threadIdx.x, w = t >> 6, lane = t & 63;
  const int lg = lane >> 4, lr = lane & 15;
  const int wm = w >> 1, wn = w & 1;
  const int m0 = blockIdx.y * 64, n0 = blockIdx.x * 128;
  f32x4 acc[2][4] = {};
  const int nsteps = K / 32;

  auto stage = [&](int buf, int ks) {
    const int k0 = ks * 32;
    {
      int c = t;
      int r = c >> 2, kc = (c & 3) * 8;
      gload_lds16(A + (size_t)(m0 + r) * K + k0 + kc, &sA[buf][c * 8]);
    }
#pragma unroll
    for (int i = 0; i < 2; ++i) {
      int c = i * 256 + t;
      int r = c >> 2, kc = (c & 3) * 8;
      int br = n0 + r;
      if (br >= N) br = N - 1;
      gload_lds16(BT + (size_t)br * K + k0 + kc, &sB[buf][c * 8]);
    }
  };

  stage(0, 0);
  __syncthreads();
  int cur = 0;
  for (int ks = 0; ks < nsteps; ++ks) {
    if (ks + 1 < nsteps) stage(cur ^ 1, ks + 1);
    bf16x8 af[2], bfr[4];
#pragma unroll
    for (int mi = 0; mi < 2; ++mi)
      af[mi] = *reinterpret_cast<const bf16x8*>(&sA[cur][(wm * 32 + mi * 16 + lr) * 32 + lg * 8]);
#pragma unroll
    for (int ni = 0; ni < 4; ++ni)
      bfr[ni] = *reinterpret_cast<const bf16x8*>(&sB[cur][(wn * 64 + ni * 16 + lr) * 32 + lg * 8]);
#pragma unroll
    for (int mi = 0; mi < 2; ++mi)
#pragma unroll
      for (int ni = 0; ni < 4; ++ni)
        acc[mi][ni] = __builtin_amdgcn_mfma_f32_16x16x32_bf16(af[mi], bfr[ni], acc[mi][ni], 0, 0, 0);
    __syncthreads();
    cur ^= 1;
  }

  const int colbase = n0 + wn * 64;
  if (colbase >= 1600) return;
  if (colbase < 1280) {
    const bool isq = colbase < 960;
    bf16* dst = isq ? qr : kr;
    const int ncols = isq ? 960 : 320;
    const int cb = isq ? colbase : colbase - 960;
#pragma unroll
    for (int mi = 0; mi < 2; ++mi) {
      const int row = m0 + wm * 32 + mi * 16 + lg * 4;
#pragma unroll
      for (int ni = 0; ni < 2; ++ni) {
        const int d = ni * 16 + lr;
#pragma unroll
        for (int r = 0; r < 4; ++r) {
          const int pos = row + r;
          float2 cs = cstab[pos * 32 + d];
          float x1 = acc[mi][ni][r], x2 = acc[mi][ni + 2][r];
          dst[(size_t)pos * ncols + cb + d] = __float2bfloat16(x1 * cs.x - x2 * cs.y);
          dst[(size_t)pos * ncols + cb + d + 32] = __float2bfloat16(x2 * cs.x + x1 * cs.y);
        }
      }
    }
  } else {
#pragma unroll
    for (int mi = 0; mi < 2; ++mi) {
      const int row = m0 + wm * 32 + mi * 16 + lg * 4;
#pragma unroll
      for (int ni = 0; ni < 4; ++ni) {
        const int vc = colbase - 1280 + ni * 16 + lr;
        ushort4 pk;
        pk.x = f2bfu(acc[mi][ni][0]);
        pk.y = f2bfu(acc[mi][ni][1]);
        pk.z = f2bfu(acc[mi][ni][2]);
        pk.w = f2bfu(acc[mi][ni][3]);
        *reinterpret_cast<ushort4*>(&vT[(size_t)vc * 2048 + row]) = pk;
      }
    }
  }
}

// ---------------- swapped-QK^T flash attention, KVBLK=64 --------------------
// grid (64 qt, 15 head, 4 chunk of 512 kv), block 64 (1 wave).
// S^T = K·Q^T; lane owns q = q0+(lane&31); two independent MFMA chains/tile.
__launch_bounds__(64)
__global__ void attn_part3(const bf16* __restrict__ q, const bf16* __restrict__ k,
                           const bf16* __restrict__ vT, float* __restrict__ pacc,
                           float* __restrict__ pml) {
  const int qt = blockIdx.x, head = blockIdx.y, c = blockIdx.z;
  if (c * 16 > qt) return;
  const int lane = threadIdx.x & 63;
  const int ql = lane & 31;
  const int hi = lane >> 5;
  const int q0 = qt * 32;
  const int kvh = head / 3;
  const int t0 = c * 8;
  const int t1 = min(t0 + 8, (q0 + 32 + 63) / 64);  // 64-kv tiles
  const int qrow = q0 + ql;
  const int kvoff = 4 * hi;

  bf16x8 qf[4];
#pragma unroll
  for (int i = 0; i < 4; ++i)
    qf[i] = *reinterpret_cast<const bf16x8*>(
        &q[(size_t)(q0 + ql) * 960 + head * 64 + i * 16 + hi * 8]);

  f32x16 acc0 = {}, acc1 = {};
  float mrun = -1e30f, lrun = 0.f;
  const size_t vrow0 = (size_t)(kvh * 64 + ql) * 2048;
  const size_t vrow1 = vrow0 + 32 * 2048;

  for (int kb = t0; kb < t1; ++kb) {
    const int kvb = kb * 64;
    // ---- K loads for both 32-kv halves ----
    bf16x8 kfa[4], kfb[4];
#pragma unroll
    for (int i = 0; i < 4; ++i) {
      kfa[i] = *reinterpret_cast<const bf16x8*>(
          &k[(size_t)(kvb + ql) * 320 + kvh * 64 + i * 16 + hi * 8]);
      kfb[i] = *reinterpret_cast<const bf16x8*>(
          &k[(size_t)(kvb + 32 + ql) * 320 + kvh * 64 + i * 16 + hi * 8]);
    }
    // ---- V loads (consumed after softmax; latency hidden under VALU) ----
    bf16x8 va0 = *reinterpret_cast<const bf16x8*>(&vT[vrow0 + kvb + hi * 8]);
    bf16x8 va1 = *reinterpret_cast<const bf16x8*>(&vT[vrow0 + kvb + 16 + hi * 8]);
    bf16x8 va2 = *reinterpret_cast<const bf16x8*>(&vT[vrow0 + kvb + 32 + hi * 8]);
    bf16x8 va3 = *reinterpret_cast<const bf16x8*>(&vT[vrow0 + kvb + 48 + hi * 8]);
    bf16x8 vb0 = *reinterpret_cast<const bf16x8*>(&vT[vrow1 + kvb + hi * 8]);
    bf16x8 vb1 = *reinterpret_cast<const bf16x8*>(&vT[vrow1 + kvb + 16 + hi * 8]);
    bf16x8 vb2 = *reinterpret_cast<const bf16x8*>(&vT[vrow1 + kvb + 32 + hi * 8]);
    bf16x8 vb3 = *reinterpret_cast<const bf16x8*>(&vT[vrow1 + kvb + 48 + hi * 8]);
    // ---- S^T: two independent chains ----
    f32x16 s0 = {}, s1 = {};
#pragma unroll
    for (int i = 0; i < 4; ++i) {
      s0 = __builtin_amdgcn_mfma_f32_32x32x16_bf16(kfa[i], qf[i], s0, 0, 0, 0);
      s1 = __builtin_amdgcn_mfma_f32_32x32x16_bf16(kfb[i], qf[i], s1, 0, 0, 0);
    }
    // ---- scale + causal mask (only diagonal-spanning tile) ----
    if (kvb + 63 > qrow) {
#pragma unroll
      for (int r = 0; r < 16; ++r) {
        const int kv = kvb + kvoff + (r & 3) + 8 * (r >> 2);
        float sv0 = s0[r] * 0.125f, sv1 = s1[r] * 0.125f;
        s0[r] = (kv > qrow) ? -1e30f : sv0;
        s1[r] = (kv + 32 > qrow) ? -1e30f : sv1;
      }
    } else {
#pragma unroll
      for (int r = 0; r < 16; ++r) { s0[r] *= 0.125f; s1[r] *= 0.125f; }
    }
    // ---- lane-local softmax (one cross-lane hop) ----
    float tm = fmaxf(s0[0], s1[0]);
#pragma unroll
    for (int r = 1; r < 16; ++r) tm = fmaxf(tm, fmaxf(s0[r], s1[r]));
    tm = fmaxf(tm, __shfl_xor(tm, 32));
    const float mn = fmaxf(mrun, tm);
    const float ef = __expf(mrun - mn);
    mrun = mn;
    float ts = 0.f;
#pragma unroll
    for (int r = 0; r < 16; ++r) {
      float p0 = __expf(s0[r] - mn), p1 = __expf(s1[r] - mn);
      s0[r] = p0; s1[r] = p1;
      ts += p0 + p1;
    }
    ts += __shfl_xor(ts, 32);
    lrun = lrun * ef + ts;
#pragma unroll
    for (int r = 0; r < 16; ++r) { acc0[r] *= ef; acc1[r] *= ef; }
    // ---- P^T -> bf16 B-fragments (cvt_pk + xor32 exchange), per half ----
    union { unsigned int u[4]; bf16x8 v; } f00, f01, f10, f11;
    {
      unsigned int a0 = cvtpk(s0[0], s0[1]), a1 = cvtpk(s0[2], s0[3]);
      unsigned int a2 = cvtpk(s0[4], s0[5]), a3 = cvtpk(s0[6], s0[7]);
      unsigned int b0 = cvtpk(s0[8], s0[9]), b1 = cvtpk(s0[10], s0[11]);
      unsigned int b2 = cvtpk(s0[12], s0[13]), b3 = cvtpk(s0[14], s0[15]);
      unsigned int x0 = __shfl_xor(a0, 32), x1 = __shfl_xor(a1, 32);
      unsigned int x2 = __shfl_xor(a2, 32), x3 = __shfl_xor(a3, 32);
      unsigned int y0 = __shfl_xor(b0, 32), y1 = __shfl_xor(b1, 32);
      unsigned int y2 = __shfl_xor(b2, 32), y3 = __shfl_xor(b3, 32);
      f00.u[0] = hi ? x2 : a0; f00.u[1] = hi ? x3 : a1;
      f00.u[2] = hi ? a2 : x0; f00.u[3] = hi ? a3 : x1;
      f01.u[0] = hi ? y2 : b0; f01.u[1] = hi ? y3 : b1;
      f01.u[2] = hi ? b2 : y0; f01.u[3] = hi ? b3 : y1;
    }
    {
      unsigned int a0 = cvtpk(s1[0], s1[1]), a1 = cvtpk(s1[2], s1[3]);
      unsigned int a2 = cvtpk(s1[4], s1[5]), a3 = cvtpk(s1[6], s1[7]);
      unsigned int b0 = cvtpk(s1[8], s1[9]), b1 = cvtpk(s1[10], s1[11]);
      unsigned int b2 = cvtpk(s1[12], s1[13]), b3 = cvtpk(s1[14], s1[15]);
      unsigned int x0 = __shfl_xor(a0, 32), x1 = __shfl_xor(a1, 32);
      unsigned int x2 = __shfl_xor(a2, 32), x3 = __shfl_xor(a3, 32);
      unsigned int y0 = __shfl_xor(b0, 32), y1 = __shfl_xor(b1, 32);
      unsigned int y2 = __shfl_xor(b2, 32), y3 = __shfl_xor(b3, 32);
      f10.u[0] = hi ? x2 : a0; f10.u[1] = hi ? x3 : a1;
      f10.u[2] = hi ? a2 : x0; f10.u[3] = hi ? a3 : x1;
      f11.u[0] = hi ? y2 : b0; f11.u[1] = hi ? y3 : b1;
      f11.u[2] = hi ? b2 : y0; f11.u[3] = hi ? b3 : y1;
    }
    // ---- O^T += V^T · P^T : two independent chains ----
    acc0 = __builtin_amdgcn_mfma_f32_32x32x16_bf16(va0, f00.v, acc0, 0, 0, 0);
    acc1 = __builtin_amdgcn_mfma_f32_32x32x16_bf16(vb0, f00.v, acc1, 0, 0, 0);
    acc0 = __builtin_amdgcn_mfma_f32_32x32x16_bf16(va1, f01.v, acc0, 0, 0, 0);
    acc1 = __builtin_amdgcn_mfma_f32_32x32x16_bf16(vb1, f01.v, acc1, 0, 0, 0);
    acc0 = __builtin_amdgcn_mfma_f32_32x32x16_bf16(va2, f10.v, acc0, 0, 0, 0);
    acc1 = __builtin_amdgcn_mfma_f32_32x32x16_bf16(vb2, f10.v, acc1, 0, 0, 0);
    acc0 = __builtin_amdgcn_mfma_f32_32x32x16_bf16(va3, f11.v, acc0, 0, 0, 0);
    acc1 = __builtin_amdgcn_mfma_f32_32x32x16_bf16(vb3, f11.v, acc1, 0, 0, 0);
  }

  // ---- write partials: pacc[job][d=64][q=32], pml[job][q][2] ----
  const size_t base = (((size_t)head * 64 + qt) * 4 + c) * 2048;
#pragma unroll
  for (int r = 0; r < 16; ++r) {
    const int row = (r & 3) + 8 * (r >> 2) + kvoff;
    pacc[base + (size_t)row * 32 + ql] = acc0[r];
    pacc[base + (size_t)(row + 32) * 32 + ql] = acc1[r];
  }
  const size_t mb = (((size_t)head * 64 + qt) * 4 + c) * 64;
  if (!hi) {
    pml[mb + ql * 2] = mrun;
    pml[mb + ql * 2 + 1] = lrun;
  }
}

// ---------------- attention merge: combine <=4 chunks -----------------------
__launch_bounds__(256)
__global__ void attn_merge2(const float* __restrict__ pacc, const float* __restrict__ pml,
                            bf16* __restrict__ ctx) {
  const int qt = blockIdx.x, head = blockIdx.y;
  const int nch = qt / 16 + 1;
  const size_t base = (((size_t)head * 64 + qt) * 4) * 2048;
  const size_t mb = (((size_t)head * 64 + qt) * 4) * 64;
  for (int i = threadIdx.x; i < 2048; i += 256) {
    const int qi = i >> 6, d = i & 63;
    float m = -1e30f;
    for (int c = 0; c < nch; ++c) m = fmaxf(m, pml[mb + c * 64 + qi * 2]);
    float lsum = 0.f, o = 0.f;
    for (int c = 0; c < nch; ++c) {
      float e = __expf(pml[mb + c * 64 + qi * 2] - m);
      lsum += pml[mb + c * 64 + qi * 2 + 1] * e;
      o += pacc[base + c * 2048 + d * 32 + qi] * e;
    }
    ctx[(size_t)(qt * 32 + qi) * 960 + head * 64 + d] = __float2bfloat16(o / lsum);
  }
}

// ---------------- launch ----------------------------------------------------
extern "C" void kernel_launch(void* const* d_in, const int* in_sizes, int n_in,
                              void* d_out, int out_size, void* d_ws, size_t ws_size,
                              hipStream_t stream) {
  const float* x  = (const float*)d_in[0];
  const float* wq = (const float*)d_in[1];
  const float* wk = (const float*)d_in[2];
  const float* wv = (const float*)d_in[3];
  const float* wo = (const float*)d_in[4];
  const float* wg = (const float*)d_in[5];
  const float* wu = (const float*)d_in[6];
  const float* wd = (const float*)d_in[7];
  const float* g1 = (const float*)d_in[8];
  const float* g2 = (const float*)d_in[9];
  float* out = (float*)d_out;

  char* ws = (char*)d_ws;
  bf16*   wT   = (bf16*)ws;                        // 0 .. 19,660,800 bytes
  float*  pacc = (float*)(ws + 19660800);          // 31,457,280 (attn partials)
  float*  pml  = (float*)(ws + 51118080);          // 983,040
  bf16*   hbuf = (bf16*)(ws + 52101120);           // 3,932,160
  bf16*   qr   = (bf16*)(ws + 56033280);           // 3,932,160
  bf16*   kr   = (bf16*)(ws + 59965440);           // 1,310,720
  bf16*   vT   = (bf16*)(ws + 61276160);           // 1,310,720
  bf16*   ctx  = (bf16*)(ws + 62586880);           // 3,932,160
  float*  x2   = (float*)(ws + 66519040);          // 7,864,320
  float2* cst  = (float2*)(ws + 74383360);         // 524,288
  bf16*   actb = (bf16*)(ws + 19660800);           // reuse pacc region (10.5MB)

  bf16* wqkvT = wT;           // 1600 rows x K=960: wq | wk | wv
  bf16* wkT  = wT + 921600;
  bf16* woT  = wT + 1536000;  // 960x960
  bf16* wguT = wT + 2457600;  // 5120x960 interleaved [gate16|up16]
  bf16* wdT  = wT + 7372800;  // 960x2560

  dim3 blk(256);
  prep_k<<<2656, blk, 0, stream>>>(wq, wk, wv, wo, wg, wu, wd,
                                   wqkvT, woT, wguT, wdT, cst);

  rmsnorm_k<<<2048, blk, 0, stream>>>(x, g1, hbuf);
  gemm_qkv<<<dim3(13, 32), blk, 0, stream>>>(hbuf, wqkvT, cst, qr, kr, vT);
  attn_part3<<<dim3(64, 15, 4), dim3(64), 0, stream>>>(qr, kr, vT, pacc, pml);
  attn_merge2<<<dim3(64, 15), blk, 0, stream>>>(pacc, pml, ctx);
  gemm_bt64<2><<<dim3(8, 32), blk, 0, stream>>>(ctx, woT, x, x2, 960, 960);
  rmsnorm_k<<<2048, blk, 0, stream>>>(x2, g2, hbuf);
  gemm_ffn<<<dim3(40, 16), blk, 0, stream>>>(hbuf, wguT, actb);
  gemm_bt64<2><<<dim3(8, 32), blk, 0, stream>>>(actb, wdT, x2, out, 960, 2560);
  rmsnorm_k<<<2048, blk, 0, stream>>>(x2, g1, hbuf);
  gemm_bt64<3><<<dim3(5, 32), blk, 0, stream>>>(hbuf, wkT, nullptr, out + 1966080, 640, 960);
}